// Round 11
// baseline (1677.285 us; speedup 1.0000x reference)
//
#include <hip/hip_runtime.h>
#include <stdint.h>

// ============================================================================
// S2S2S LSTM forecaster, MI355X.  Round 11 = round-8 structure (16 blocks x
// 512 thr, best: 822us enc) with ONE change: Whh fragments kt1..kt5 are held
// in AGPRs and fed to MFMA DIRECTLY via inline asm ("a" constraint on the A
// operand) -> eliminates the compiler's v_accvgpr_read shuffling (~1300
// cyc/SIMD/step). kt0 stays builtin+VGPR (chain start, compiler-managed
// hazards); kt6,7 stay builtin+LDS (chain end). "+v" on acc pins the
// accumulators to VGPRs (no accvgpr round-trips). Pattern validated in R3.
// Inner math identical to round 8 (prescaled Whh + xp srcC, merged rcp).
// Output: cols 0..75 = future-decoder head, 76..90 = 0 (ref overwrites out_f).
// ============================================================================

typedef __attribute__((ext_vector_type(8))) short short8;  // 8 x bf16
typedef __attribute__((ext_vector_type(4))) float f32x4;   // MFMA acc
typedef __attribute__((ext_vector_type(2))) unsigned int u32x2;

#define L2E 1.4426950408889634f

__device__ __forceinline__ uint16_t f2bf(float f) {  // fp32 -> bf16 bits, RNE
  uint32_t x = __float_as_uint(f);
  x += 0x7fffu + ((x >> 16) & 1u);
  return (uint16_t)(x >> 16);
}
__device__ __forceinline__ uint32_t pk2(float a, float b) {
  return (uint32_t)f2bf(a) | ((uint32_t)f2bf(b) << 16);
}
__device__ __forceinline__ uint32_t cvtpk(float lo, float hi) {  // 1-inst pack
  uint32_t r;
  asm("v_cvt_pk_bf16_f32 %0, %1, %2" : "=v"(r) : "v"(lo), "v"(hi));
  return r;
}
__device__ __forceinline__ float bfhalf(uint32_t w, int hi) {  // bf16 -> fp32
  return __uint_as_float(hi ? (w & 0xffff0000u) : (w << 16));
}
__device__ __forceinline__ f32x4 MFMA(short8 a, short8 b, f32x4 c) {
  return __builtin_amdgcn_mfma_f32_16x16x32_bf16(a, b, c, 0, 0, 0);
}
// MFMA with the A operand (Whh frag) pinned in AGPRs, acc pinned in VGPRs.
// Mid-chain only (srcC from previous MFMA, D to next) -> no manual nops.
__device__ __forceinline__ f32x4 mfma_aA(short8 a, short8 b, f32x4 c) {
  asm("v_mfma_f32_16x16x32_bf16 %0, %1, %2, %0" : "+v"(c) : "a"(a), "v"(b));
  return c;
}
__device__ __forceinline__ float ex2(float x) { return __builtin_amdgcn_exp2f(x); }
__device__ __forceinline__ float rcp(float x) { return __builtin_amdgcn_rcpf(x); }

// Barrier waiting only LDS ops (lgkmcnt), NOT vmcnt: xp prefetch loads stay
// in flight across steps. sched_barriers fence code motion.
__device__ __forceinline__ void lgkm_barrier() {
  __builtin_amdgcn_sched_barrier(0);
  asm volatile("s_waitcnt lgkmcnt(0)" ::: "memory");
  __builtin_amdgcn_s_barrier();
  __builtin_amdgcn_sched_barrier(0);
}

// ---------------------------------------------------------------------------
__global__ void init_kernel(float* c_state, uint16_t* h_state, float* out) {
  int i = blockIdx.x * 256 + threadIdx.x;
  if (i < 65536) { c_state[i] = 0.f; h_state[i] = 0; }
  if (i < 256 * 91) out[i] = 0.f;
}

// ---------------------------------------------------------------------------
// xproj (unchanged): transposed, pre-scaled C^T fragments,
// xp[tc][btile][rowtile][lane][2], value = (x@Wih^T+b)*(g? +2log2e : -log2e).
// ---------------------------------------------------------------------------
template <int DIN>
__global__ __launch_bounds__(512) void xproj_kernel(
    const float* __restrict__ x, const float* __restrict__ Wih,
    const float* __restrict__ bias, uint32_t* __restrict__ xp,
    int t0, int T) {
  const int tid = threadIdx.x, w = tid >> 6, l = tid & 63;
  const int l16 = l & 15, lg = l >> 4;
  const int tc = blockIdx.x >> 1;
  const int sub = blockIdx.x & 1;
  const int t = t0 + tc;
  constexpr int KT = (DIN + 31) / 32;

  short8 bfr[8][KT];
  float4 bias4[8];
#pragma unroll
  for (int ni = 0; ni < 8; ++ni) {
    const int n = (w * 8 + ni) * 16 + l16;
    bias4[ni] = *(const float4*)&bias[(w * 8 + ni) * 16 + lg * 4];
#pragma unroll
    for (int kt = 0; kt < KT; ++kt) {
      const int k0 = kt * 32 + lg * 8;
      short8 fr;
#pragma unroll
      for (int e = 0; e < 8; ++e) fr[e] = 0;
      if (k0 + 8 <= DIN) {
        const float* s = Wih + (size_t)n * DIN + k0;
#pragma unroll
        for (int e = 0; e < 8; ++e) fr[e] = (short)f2bf(s[e]);
      }
      bfr[ni][kt] = fr;
    }
  }

  for (int mi = 0; mi < 8; ++mi) {
    const int btile = sub * 8 + mi;
    const int b = btile * 16 + l16;
    short8 af[KT];
#pragma unroll
    for (int kt = 0; kt < KT; ++kt) {
      const int k0 = kt * 32 + lg * 8;
      short8 fr;
#pragma unroll
      for (int e = 0; e < 8; ++e) fr[e] = 0;
      if (k0 + 8 <= DIN) {
        const float* s = x + ((size_t)b * T + t) * DIN + k0;
#pragma unroll
        for (int e = 0; e < 8; ++e) fr[e] = (short)f2bf(s[e]);
      }
      af[kt] = fr;
    }
#pragma unroll
    for (int ni = 0; ni < 8; ++ni) {
      f32x4 acc = {0.f, 0.f, 0.f, 0.f};
#pragma unroll
      for (int kt = 0; kt < KT; ++kt) acc = MFMA(bfr[ni][kt], af[kt], acc);
      const int nt = w * 8 + ni;
      const float sc = ((nt >> 4) == 2) ? (2.f * L2E) : -L2E;
      size_t idx = ((((size_t)tc * 16 + btile) * 64 + nt) * 64 + l) * 2;
      u32x2 v;
      v[0] = pk2((acc[0] + bias4[ni].x) * sc, (acc[1] + bias4[ni].y) * sc);
      v[1] = pk2((acc[2] + bias4[ni].z) * sc, (acc[3] + bias4[ni].w) * sc);
      *(u32x2*)(xp + idx) = v;
    }
  }
}

// ---------------------------------------------------------------------------
// Recurrent kernel: 16 blocks x 512 thr. Wave w owns hidden cols [32w,32w+32)
// (2 row-tiles nt), all 4 gates. Gate-row tile (g,nt) = g*16 + w*2 + nt.
// Transposed: lane = (hidden col (w*2+nt)*16+lg*4+j, batch l16).
// Whh frags PRE-SCALED by gate constant. Storage per tile = g*2+nt:
//   kt0        -> VGPR  bv_v[tile]            (builtin, chain start)
//   kt1..kt5   -> AGPR  ba[tile*5 + kt-1]     (inline-asm MFMA, mid-chain)
//   kt6,kt7    -> LDS   B_lds[(w*16+(kt-6)*8+tile)*64+l]  (builtin, chain end)
// acc init = unpacked prescaled xpf (srcC); "+v" pins acc to VGPRs.
// ---------------------------------------------------------------------------
template <int DO_HEAD>
__global__ __launch_bounds__(512, 2) void rec_kernel(
    const uint32_t* __restrict__ xp, const float* __restrict__ Whh,
    float* __restrict__ c_state, uint16_t* __restrict__ h_state,
    float* __restrict__ out, const float* __restrict__ headW,
    const float* __restrict__ headb, int ct, int tcol0) {
  __shared__ short8 B_lds[8 * 16 * 64];   // 131072 B
  __shared__ uint16_t h_lds[2][16][264];  // 16896 B (double-buffered, pad 264)
  __shared__ float headbuf[2][16][8];     // 1024 B   (total 148992 B)

  const int tid = threadIdx.x, w = tid >> 6, l = tid & 63;
  const int l16 = l & 15, lg = l >> 4;
  const int blk = blockIdx.x, b0 = blk * 16;

  // ---- Whh -> prescaled bf16 fragments: VGPR / AGPR / LDS ----
  short8 bv_v[8];   // kt0 per tile
  short8 ba[40];    // kt1..5 per tile, AGPR-pinned (160 AGPRs)
#pragma unroll
  for (int g = 0; g < 4; ++g) {
    const float wsc = (g == 2) ? (2.f * L2E) : -L2E;  // gate order i,f,g,o
#pragma unroll
    for (int nt = 0; nt < 2; ++nt)
#pragma unroll
      for (int kt = 0; kt < 8; ++kt) {
        const int row = (g * 16 + w * 2 + nt) * 16 + l16;
        const float* s = Whh + (size_t)row * 256 + kt * 32 + lg * 8;
        short8 fr;
#pragma unroll
        for (int e = 0; e < 8; ++e) fr[e] = (short)f2bf(s[e] * wsc);
        const int tile = g * 2 + nt;
        if (kt == 0) {
          bv_v[tile] = fr;
        } else if (kt <= 5) {
          asm("" : "+a"(fr));                 // pin to AGPR class
          ba[tile * 5 + (kt - 1)] = fr;
        } else {
          B_lds[(w * 16 + (kt - 6) * 8 + tile) * 64 + l] = fr;
        }
      }
  }

  // ---- state load (vectorized; lane owns (4 cols x 1 batch) per nt) ----
  float c_reg[2][4];
#pragma unroll
  for (int nt = 0; nt < 2; ++nt) {
    float4 c4 = *(const float4*)&c_state[(size_t)(b0 + l16) * 256 +
                                         (w * 2 + nt) * 16 + lg * 4];
    c_reg[nt][0] = c4.x; c_reg[nt][1] = c4.y;
    c_reg[nt][2] = c4.z; c_reg[nt][3] = c4.w;
  }
  for (int idx = tid; idx < 16 * 256; idx += 512)
    h_lds[0][idx >> 8][idx & 255] = h_state[(size_t)(b0 + (idx >> 8)) * 256 + (idx & 255)];
  float4 hw4[2];
#pragma unroll
  for (int nt = 0; nt < 2; ++nt)
    hw4[nt] = *(const float4*)&headW[(w * 2 + nt) * 16 + lg * 4];
  const float hb = headb[0];

  // ---- xp prefetch for t=0 ----
  const uint32_t* xpb = xp + ((size_t)(blk * 64 + w * 2) * 64 + l) * 2;
  u32x2 xpf[2][4];
#pragma unroll
  for (int nt = 0; nt < 2; ++nt)
#pragma unroll
    for (int g = 0; g < 4; ++g)
      xpf[nt][g] = *(const u32x2*)(xpb + (size_t)g * 2048 + nt * 128);

  __syncthreads();

  for (int t = 0; t < ct; ++t) {
    const int cur = t & 1, nxt = cur ^ 1;
    const int tn = (t + 1 < ct) ? t + 1 : t;
    float hp = 0.f;

#pragma unroll
    for (int nt = 0; nt < 2; ++nt) {
      // ---- acc init from prescaled xp (srcC) ----
      f32x4 acc[4];
#pragma unroll
      for (int g = 0; g < 4; ++g) {
        f32x4 ai;
        ai[0] = bfhalf(xpf[nt][g][0], 0);
        ai[1] = bfhalf(xpf[nt][g][0], 1);
        ai[2] = bfhalf(xpf[nt][g][1], 0);
        ai[3] = bfhalf(xpf[nt][g][1], 1);
        acc[g] = ai;
      }
      // kt0: builtin, VGPR frags (chain start; compiler-managed hazards)
      {
        short8 hf = *(const short8*)(&h_lds[cur][l16][lg * 8]);
#pragma unroll
        for (int g = 0; g < 4; ++g)
          acc[g] = MFMA(bv_v[g * 2 + nt], hf, acc[g]);
      }
      // kt1..5: inline-asm MFMA, A from AGPR (mid-chain, D->srcC only)
#pragma unroll
      for (int kt = 1; kt <= 5; ++kt) {
        short8 hf = *(const short8*)(&h_lds[cur][l16][kt * 32 + lg * 8]);
#pragma unroll
        for (int g = 0; g < 4; ++g)
          acc[g] = mfma_aA(ba[(g * 2 + nt) * 5 + (kt - 1)], hf, acc[g]);
      }
      // kt6,7: builtin, LDS frags (chain end)
#pragma unroll
      for (int kt = 6; kt <= 7; ++kt) {
        short8 hf = *(const short8*)(&h_lds[cur][l16][kt * 32 + lg * 8]);
#pragma unroll
        for (int g = 0; g < 4; ++g)
          acc[g] = MFMA(B_lds[(w * 16 + (kt - 6) * 8 + g * 2 + nt) * 64 + l], hf, acc[g]);
      }

      // ---- activations: acc[g][j] = scaled gate arg; i,f,g,o ----
      float hv[4];
#pragma unroll
      for (int j = 0; j < 4; ++j) {
        float ei = ex2(acc[0][j]);            // e^{-I}
        float ef = ex2(acc[1][j]);            // e^{-F}
        float eg = ex2(acc[2][j]);            // e^{+2G}
        float eo = ex2(acc[3][j]);            // e^{-O}
        float eip = 1.f + ei, egp = eg + 1.f, efp = 1.f + ef;
        float d1 = eip * egp;
        float R = rcp(d1 * efp);              // 1/((1+ei)(eg+1)(1+ef))
        float sitg = (eg - 1.f) * efp * R;    // sig(I)tanh(G)
        float cc = fmaf(c_reg[nt][j] * d1, R, sitg);  // + sig(F)*c
        c_reg[nt][j] = cc;
        float ec = ex2(cc * (2.f * L2E));     // e^{2c}
        float hh = (ec - 1.f) * rcp((1.f + eo) * (ec + 1.f));
        hv[j] = hh;
      }
      if (DO_HEAD) {
        hp = fmaf(hv[0], hw4[nt].x, hp); hp = fmaf(hv[1], hw4[nt].y, hp);
        hp = fmaf(hv[2], hw4[nt].z, hp); hp = fmaf(hv[3], hw4[nt].w, hp);
      }
      // packed h write: 4 contiguous bf16 cols -> one b64 store
      {
        u32x2 hwrd;
        hwrd[0] = cvtpk(hv[0], hv[1]);
        hwrd[1] = cvtpk(hv[2], hv[3]);
        *(u32x2*)(&h_lds[nxt][l16][(w * 2 + nt) * 16 + lg * 4]) = hwrd;
      }
      // prefetch next step's xp for this nt (vmcnt never drained in loop)
#pragma unroll
      for (int g = 0; g < 4; ++g)
        xpf[nt][g] = *(const u32x2*)(xpb + (size_t)tn * 131072 + g * 2048 + nt * 128);
    }

    if (DO_HEAD) {
      float s = hp;
      s += __shfl_xor(s, 16);
      s += __shfl_xor(s, 32);
      if (lg == 0) headbuf[t & 1][l16][w] = s;
    }

    lgkm_barrier();  // h[nxt] (and headbuf) visible; all cur-reads done

    if (DO_HEAD) {
      if (tid < 16) {
        const float* hbp = headbuf[t & 1][tid];
        float s = hbp[0] + hbp[1] + hbp[2] + hbp[3] + hbp[4] + hbp[5] + hbp[6] + hbp[7];
        out[(size_t)(b0 + tid) * 91 + (tcol0 + t)] = s + hb;
      }
    }
  }

  // ---- state writeback ----
#pragma unroll
  for (int nt = 0; nt < 2; ++nt) {
    float4 c4 = {c_reg[nt][0], c_reg[nt][1], c_reg[nt][2], c_reg[nt][3]};
    *(float4*)&c_state[(size_t)(b0 + l16) * 256 + (w * 2 + nt) * 16 + lg * 4] = c4;
  }
  for (int idx = tid; idx < 16 * 256; idx += 512)
    h_state[(size_t)(b0 + (idx >> 8)) * 256 + (idx & 255)] = h_lds[ct & 1][idx >> 8][idx & 255];
}

// ---------------------------------------------------------------------------
extern "C" void kernel_launch(void* const* d_in, const int* in_sizes, int n_in,
                              void* d_out, int out_size, void* d_ws, size_t ws_size,
                              hipStream_t stream) {
  const float* headW = (const float*)d_in[12];
  const float* headb = (const float*)d_in[13];
  float* out = (float*)d_out;

  char* ws = (char*)d_ws;
  float* c_state = (float*)ws;                      // 256 KB
  uint16_t* h_state = (uint16_t*)(ws + 262144);     // 128 KB
  uint32_t* xp = (uint32_t*)(ws + 393216);          // chunk buffer, 512 KB per t

  int ct_max = 1;
  if (ws_size > 393216 + 512 * 1024) {
    size_t c = (ws_size - 393216) / (512 * 1024);
    ct_max = (c > 365) ? 365 : (int)c;
  }

  init_kernel<<<256, 256, 0, stream>>>(c_state, h_state, out);

  struct Phase { const float* x; const float* Wih; const float* Whh; const float* b; int T; int D; int head; };
  Phase ph[3] = {
      {(const float*)d_in[0], (const float*)d_in[3], (const float*)d_in[4], (const float*)d_in[5],
       in_sizes[0] / (256 * 64), 64, 0},
      {(const float*)d_in[1], (const float*)d_in[6], (const float*)d_in[7], (const float*)d_in[8],
       in_sizes[1] / (256 * 32), 32, 0},
      {(const float*)d_in[2], (const float*)d_in[9], (const float*)d_in[10], (const float*)d_in[11],
       in_sizes[2] / (256 * 16), 16, 1},
  };

  for (int pi = 0; pi < 3; ++pi) {
    const Phase& P = ph[pi];
    for (int t0 = 0; t0 < P.T; t0 += ct_max) {
      int ct = (P.T - t0 < ct_max) ? (P.T - t0) : ct_max;
      dim3 g(ct * 2);
      if (P.D == 64)
        xproj_kernel<64><<<g, 512, 0, stream>>>(P.x, P.Wih, P.b, xp, t0, P.T);
      else if (P.D == 32)
        xproj_kernel<32><<<g, 512, 0, stream>>>(P.x, P.Wih, P.b, xp, t0, P.T);
      else
        xproj_kernel<16><<<g, 512, 0, stream>>>(P.x, P.Wih, P.b, xp, t0, P.T);
      if (P.head)
        rec_kernel<1><<<16, 512, 0, stream>>>(xp, P.Whh, c_state, h_state, out,
                                              headW, headb, ct, t0);
      else
        rec_kernel<0><<<16, 512, 0, stream>>>(xp, P.Whh, c_state, h_state, out,
                                              headW, headb, ct, t0);
    }
  }
}

// Round 12
// 1345.615 us; speedup vs baseline: 1.2465x; 1.2465x over previous
//
#include <hip/hip_runtime.h>
#include <stdint.h>

// ============================================================================
// S2S2S LSTM forecaster, MI355X.  Round 12: launch fusion around the proven
// round-8 inner loop (822us enc, best).
//   - rec_fused: ONE launch runs enc+decf+decu phases back-to-back; Whh
//     fragments reloaded per phase inside the kernel; h stays in LDS and c in
//     registers across phases (no HBM state round-trips). Step body verbatim
//     round 8; DO_HEAD is a uniform runtime flag.
//   - 3 xproj launches fill disjoint xp slices up front (needs 234MB ws).
//   - If ws_size < needed: verbatim round-8 fallback path (chunked, proven).
//   - cvtpk packing (1 inst/bf16-pair) in xproj + weight prologues.
// Output: cols 0..75 = future-decoder head, 76..90 = 0 (ref overwrites out_f).
// ============================================================================

typedef __attribute__((ext_vector_type(8))) short short8;  // 8 x bf16
typedef __attribute__((ext_vector_type(4))) float f32x4;   // MFMA acc
typedef __attribute__((ext_vector_type(2))) unsigned int u32x2;
typedef __attribute__((ext_vector_type(4))) unsigned int u32x4;

#define L2E 1.4426950408889634f

__device__ __forceinline__ uint16_t f2bf(float f) {  // fp32 -> bf16 bits, RNE
  uint32_t x = __float_as_uint(f);
  x += 0x7fffu + ((x >> 16) & 1u);
  return (uint16_t)(x >> 16);
}
__device__ __forceinline__ uint32_t cvtpk(float lo, float hi) {  // 1-inst pack
  uint32_t r;
  asm("v_cvt_pk_bf16_f32 %0, %1, %2" : "=v"(r) : "v"(lo), "v"(hi));
  return r;
}
__device__ __forceinline__ float bfhalf(uint32_t w, int hi) {  // bf16 -> fp32
  return __uint_as_float(hi ? (w & 0xffff0000u) : (w << 16));
}
__device__ __forceinline__ f32x4 MFMA(short8 a, short8 b, f32x4 c) {
  return __builtin_amdgcn_mfma_f32_16x16x32_bf16(a, b, c, 0, 0, 0);
}
__device__ __forceinline__ float ex2(float x) { return __builtin_amdgcn_exp2f(x); }
__device__ __forceinline__ float rcp(float x) { return __builtin_amdgcn_rcpf(x); }

// pack 8 consecutive floats (16B-aligned) * scale -> short8 of bf16
__device__ __forceinline__ short8 pack8s(const float* s, float sc) {
  float4 q0 = *(const float4*)s, q1 = *(const float4*)(s + 4);
  u32x4 t;
  t[0] = cvtpk(q0.x * sc, q0.y * sc);
  t[1] = cvtpk(q0.z * sc, q0.w * sc);
  t[2] = cvtpk(q1.x * sc, q1.y * sc);
  t[3] = cvtpk(q1.z * sc, q1.w * sc);
  return *(short8*)&t;
}

// Barrier waiting only LDS ops (lgkmcnt), NOT vmcnt: xp prefetch loads stay
// in flight across steps. sched_barriers fence code motion.
__device__ __forceinline__ void lgkm_barrier() {
  __builtin_amdgcn_sched_barrier(0);
  asm volatile("s_waitcnt lgkmcnt(0)" ::: "memory");
  __builtin_amdgcn_s_barrier();
  __builtin_amdgcn_sched_barrier(0);
}

// ---------------------------------------------------------------------------
__global__ void init_kernel(float* c_state, uint16_t* h_state, float* out) {
  int i = blockIdx.x * 256 + threadIdx.x;
  if (i < 65536) { c_state[i] = 0.f; h_state[i] = 0; }
  if (i < 256 * 91) out[i] = 0.f;
}

// ---------------------------------------------------------------------------
// xproj: transposed, pre-scaled C^T fragments,
// xp[tc][btile][rowtile][lane][2], value = (x@Wih^T+b)*(g? +2log2e : -log2e).
// ---------------------------------------------------------------------------
template <int DIN>
__global__ __launch_bounds__(512) void xproj_kernel(
    const float* __restrict__ x, const float* __restrict__ Wih,
    const float* __restrict__ bias, uint32_t* __restrict__ xp,
    int t0, int T) {
  const int tid = threadIdx.x, w = tid >> 6, l = tid & 63;
  const int l16 = l & 15, lg = l >> 4;
  const int tc = blockIdx.x >> 1;
  const int sub = blockIdx.x & 1;
  const int t = t0 + tc;
  constexpr int KT = (DIN + 31) / 32;

  short8 bfr[8][KT];
  float4 bias4[8];
#pragma unroll
  for (int ni = 0; ni < 8; ++ni) {
    const int n = (w * 8 + ni) * 16 + l16;
    bias4[ni] = *(const float4*)&bias[(w * 8 + ni) * 16 + lg * 4];
#pragma unroll
    for (int kt = 0; kt < KT; ++kt) {
      const int k0 = kt * 32 + lg * 8;
      short8 fr;
#pragma unroll
      for (int e = 0; e < 8; ++e) fr[e] = 0;
      if (k0 + 8 <= DIN) fr = pack8s(Wih + (size_t)n * DIN + k0, 1.f);
      bfr[ni][kt] = fr;
    }
  }

  for (int mi = 0; mi < 8; ++mi) {
    const int btile = sub * 8 + mi;
    const int b = btile * 16 + l16;
    short8 af[KT];
#pragma unroll
    for (int kt = 0; kt < KT; ++kt) {
      const int k0 = kt * 32 + lg * 8;
      short8 fr;
#pragma unroll
      for (int e = 0; e < 8; ++e) fr[e] = 0;
      if (k0 + 8 <= DIN) fr = pack8s(x + ((size_t)b * T + t) * DIN + k0, 1.f);
      af[kt] = fr;
    }
#pragma unroll
    for (int ni = 0; ni < 8; ++ni) {
      f32x4 acc = {0.f, 0.f, 0.f, 0.f};
#pragma unroll
      for (int kt = 0; kt < KT; ++kt) acc = MFMA(bfr[ni][kt], af[kt], acc);
      const int nt = w * 8 + ni;
      const float sc = ((nt >> 4) == 2) ? (2.f * L2E) : -L2E;
      size_t idx = ((((size_t)tc * 16 + btile) * 64 + nt) * 64 + l) * 2;
      u32x2 v;
      v[0] = cvtpk((acc[0] + bias4[ni].x) * sc, (acc[1] + bias4[ni].y) * sc);
      v[1] = cvtpk((acc[2] + bias4[ni].z) * sc, (acc[3] + bias4[ni].w) * sc);
      *(u32x2*)(xp + idx) = v;
    }
  }
}

// ---------------------------------------------------------------------------
// rec_fused: 16 blocks x 512 thr; runs all 3 phases in one launch.
// Wave w owns hidden cols [32w,32w+32) (2 row-tiles nt), all 4 gates.
// Gate-row tile (g,nt) = g*16 + w*2 + nt; lane = (col, batch l16).
// Whh frags PRE-SCALED; kt<=5 -> bv[(g*2+nt)*6+kt]; kt6,7 -> B_lds.
// acc init = unpacked prescaled xpf (srcC). Step body = round 8 verbatim.
// ---------------------------------------------------------------------------
__global__ __launch_bounds__(512, 2) void rec_fused(
    const uint32_t* __restrict__ xp0, const uint32_t* __restrict__ xp1,
    const uint32_t* __restrict__ xp2, const float* __restrict__ Whh0,
    const float* __restrict__ Whh1, const float* __restrict__ Whh2,
    float* __restrict__ out, const float* __restrict__ headW,
    const float* __restrict__ headb, int T0, int T1, int T2) {
  __shared__ short8 B_lds[8 * 16 * 64];   // 131072 B
  __shared__ uint16_t h_lds[2][16][264];  // 16896 B (double-buffered, pad 264)
  __shared__ float headbuf[2][16][8];     // 1024 B

  const int tid = threadIdx.x, w = tid >> 6, l = tid & 63;
  const int l16 = l & 15, lg = l >> 4;
  const int blk = blockIdx.x, b0 = blk * 16;

  // ---- zero initial state (h in LDS buf 0, c in regs) ----
  float c_reg[2][4];
#pragma unroll
  for (int nt = 0; nt < 2; ++nt)
#pragma unroll
    for (int j = 0; j < 4; ++j) c_reg[nt][j] = 0.f;
  for (int idx = tid; idx < 16 * 264; idx += 512)
    ((uint16_t*)h_lds)[idx] = 0;   // h_lds[0] flat
  float4 hw4[2];
#pragma unroll
  for (int nt = 0; nt < 2; ++nt)
    hw4[nt] = *(const float4*)&headW[(w * 2 + nt) * 16 + lg * 4];
  const float hb = headb[0];

  int cur = 0;
  for (int p = 0; p < 3; ++p) {
    const float* Whh = (p == 0) ? Whh0 : (p == 1) ? Whh1 : Whh2;
    const uint32_t* xp = (p == 0) ? xp0 : (p == 1) ? xp1 : xp2;
    const int ct = (p == 0) ? T0 : (p == 1) ? T1 : T2;
    const bool headf = (p == 2);

    // ---- Whh -> prescaled bf16 fragments: regs (kt0..5) / LDS (kt6,7) ----
    // (safe vs previous phase: all B_lds reads retired before its last
    //  lgkm_barrier; __syncthreads below publishes the new fragments)
    short8 bv[48];
#pragma unroll
    for (int g = 0; g < 4; ++g) {
      const float wsc = (g == 2) ? (2.f * L2E) : -L2E;  // gate order i,f,g,o
#pragma unroll
      for (int nt = 0; nt < 2; ++nt)
#pragma unroll
        for (int kt = 0; kt < 8; ++kt) {
          const int row = (g * 16 + w * 2 + nt) * 16 + l16;
          short8 fr = pack8s(Whh + (size_t)row * 256 + kt * 32 + lg * 8, wsc);
          const int tile = g * 2 + nt;
          if (kt <= 5) bv[tile * 6 + kt] = fr;
          else B_lds[(w * 16 + (kt - 6) * 8 + tile) * 64 + l] = fr;
        }
    }

    // ---- xp prefetch for t=0 of this phase ----
    const uint32_t* xpb = xp + ((size_t)(blk * 64 + w * 2) * 64 + l) * 2;
    u32x2 xpf[2][4];
#pragma unroll
    for (int nt = 0; nt < 2; ++nt)
#pragma unroll
      for (int g = 0; g < 4; ++g)
        xpf[nt][g] = *(const u32x2*)(xpb + (size_t)g * 2048 + nt * 128);

    __syncthreads();

    for (int t = 0; t < ct; ++t) {
      const int nxt = cur ^ 1;
      const int tn = (t + 1 < ct) ? t + 1 : t;
      float hp = 0.f;

#pragma unroll
      for (int nt = 0; nt < 2; ++nt) {
        // ---- acc init from prescaled xp (srcC) ----
        f32x4 acc[4];
#pragma unroll
        for (int g = 0; g < 4; ++g) {
          f32x4 ai;
          ai[0] = bfhalf(xpf[nt][g][0], 0);
          ai[1] = bfhalf(xpf[nt][g][0], 1);
          ai[2] = bfhalf(xpf[nt][g][1], 0);
          ai[3] = bfhalf(xpf[nt][g][1], 1);
          acc[g] = ai;
        }
#pragma unroll
        for (int kt = 0; kt <= 5; ++kt) {
          short8 hf = *(const short8*)(&h_lds[cur][l16][kt * 32 + lg * 8]);
#pragma unroll
          for (int g = 0; g < 4; ++g)
            acc[g] = MFMA(bv[(g * 2 + nt) * 6 + kt], hf, acc[g]);
        }
#pragma unroll
        for (int kt = 6; kt <= 7; ++kt) {
          short8 hf = *(const short8*)(&h_lds[cur][l16][kt * 32 + lg * 8]);
#pragma unroll
          for (int g = 0; g < 4; ++g)
            acc[g] = MFMA(B_lds[(w * 16 + (kt - 6) * 8 + g * 2 + nt) * 64 + l], hf, acc[g]);
        }

        // ---- activations: acc[g][j] = scaled gate arg; i,f,g,o ----
        float hv[4];
#pragma unroll
        for (int j = 0; j < 4; ++j) {
          float ei = ex2(acc[0][j]);            // e^{-I}
          float ef = ex2(acc[1][j]);            // e^{-F}
          float eg = ex2(acc[2][j]);            // e^{+2G}
          float eo = ex2(acc[3][j]);            // e^{-O}
          float eip = 1.f + ei, egp = eg + 1.f, efp = 1.f + ef;
          float d1 = eip * egp;
          float R = rcp(d1 * efp);              // 1/((1+ei)(eg+1)(1+ef))
          float sitg = (eg - 1.f) * efp * R;    // sig(I)tanh(G)
          float cc = fmaf(c_reg[nt][j] * d1, R, sitg);  // + sig(F)*c
          c_reg[nt][j] = cc;
          float ec = ex2(cc * (2.f * L2E));     // e^{2c}
          float hh = (ec - 1.f) * rcp((1.f + eo) * (ec + 1.f));
          hv[j] = hh;
        }
        if (headf) {
          hp = fmaf(hv[0], hw4[nt].x, hp); hp = fmaf(hv[1], hw4[nt].y, hp);
          hp = fmaf(hv[2], hw4[nt].z, hp); hp = fmaf(hv[3], hw4[nt].w, hp);
        }
        // packed h write: 4 contiguous bf16 cols -> one b64 store
        {
          u32x2 hwrd;
          hwrd[0] = cvtpk(hv[0], hv[1]);
          hwrd[1] = cvtpk(hv[2], hv[3]);
          *(u32x2*)(&h_lds[nxt][l16][(w * 2 + nt) * 16 + lg * 4]) = hwrd;
        }
        // prefetch next step's xp for this nt (vmcnt never drained in loop)
#pragma unroll
        for (int g = 0; g < 4; ++g)
          xpf[nt][g] = *(const u32x2*)(xpb + (size_t)tn * 131072 + g * 2048 + nt * 128);
      }

      if (headf) {
        float s = hp;
        s += __shfl_xor(s, 16);
        s += __shfl_xor(s, 32);
        if (lg == 0) headbuf[t & 1][l16][w] = s;
      }

      lgkm_barrier();  // h[nxt] (and headbuf) visible; all cur-reads done

      if (headf) {
        if (tid < 16) {
          const float* hbp = headbuf[t & 1][tid];
          float s = hbp[0] + hbp[1] + hbp[2] + hbp[3] + hbp[4] + hbp[5] + hbp[6] + hbp[7];
          out[(size_t)(b0 + tid) * 91 + t] = s + hb;
        }
      }
      cur = nxt;
    }
  }
}

// ---------------------------------------------------------------------------
// Fallback rec kernel: verbatim round 8 (chunked path, proven 1264us).
// ---------------------------------------------------------------------------
template <int DO_HEAD>
__global__ __launch_bounds__(512, 2) void rec_kernel(
    const uint32_t* __restrict__ xp, const float* __restrict__ Whh,
    float* __restrict__ c_state, uint16_t* __restrict__ h_state,
    float* __restrict__ out, const float* __restrict__ headW,
    const float* __restrict__ headb, int ct, int tcol0) {
  __shared__ short8 B_lds[8 * 16 * 64];
  __shared__ uint16_t h_lds[2][16][264];
  __shared__ float headbuf[2][16][8];

  const int tid = threadIdx.x, w = tid >> 6, l = tid & 63;
  const int l16 = l & 15, lg = l >> 4;
  const int blk = blockIdx.x, b0 = blk * 16;

  short8 bv[48];
#pragma unroll
  for (int g = 0; g < 4; ++g) {
    const float wsc = (g == 2) ? (2.f * L2E) : -L2E;
#pragma unroll
    for (int nt = 0; nt < 2; ++nt)
#pragma unroll
      for (int kt = 0; kt < 8; ++kt) {
        const int row = (g * 16 + w * 2 + nt) * 16 + l16;
        const float* s = Whh + (size_t)row * 256 + kt * 32 + lg * 8;
        short8 fr;
#pragma unroll
        for (int e = 0; e < 8; ++e) fr[e] = (short)f2bf(s[e] * wsc);
        const int tile = g * 2 + nt;
        if (kt <= 5) bv[tile * 6 + kt] = fr;
        else B_lds[(w * 16 + (kt - 6) * 8 + tile) * 64 + l] = fr;
      }
  }

  float c_reg[2][4];
#pragma unroll
  for (int nt = 0; nt < 2; ++nt) {
    float4 c4 = *(const float4*)&c_state[(size_t)(b0 + l16) * 256 +
                                         (w * 2 + nt) * 16 + lg * 4];
    c_reg[nt][0] = c4.x; c_reg[nt][1] = c4.y;
    c_reg[nt][2] = c4.z; c_reg[nt][3] = c4.w;
  }
  for (int idx = tid; idx < 16 * 256; idx += 512)
    h_lds[0][idx >> 8][idx & 255] = h_state[(size_t)(b0 + (idx >> 8)) * 256 + (idx & 255)];
  float4 hw4[2];
#pragma unroll
  for (int nt = 0; nt < 2; ++nt)
    hw4[nt] = *(const float4*)&headW[(w * 2 + nt) * 16 + lg * 4];
  const float hb = headb[0];

  const uint32_t* xpb = xp + ((size_t)(blk * 64 + w * 2) * 64 + l) * 2;
  u32x2 xpf[2][4];
#pragma unroll
  for (int nt = 0; nt < 2; ++nt)
#pragma unroll
    for (int g = 0; g < 4; ++g)
      xpf[nt][g] = *(const u32x2*)(xpb + (size_t)g * 2048 + nt * 128);

  __syncthreads();

  for (int t = 0; t < ct; ++t) {
    const int cur = t & 1, nxt = cur ^ 1;
    const int tn = (t + 1 < ct) ? t + 1 : t;
    float hp = 0.f;

#pragma unroll
    for (int nt = 0; nt < 2; ++nt) {
      f32x4 acc[4];
#pragma unroll
      for (int g = 0; g < 4; ++g) {
        f32x4 ai;
        ai[0] = bfhalf(xpf[nt][g][0], 0);
        ai[1] = bfhalf(xpf[nt][g][0], 1);
        ai[2] = bfhalf(xpf[nt][g][1], 0);
        ai[3] = bfhalf(xpf[nt][g][1], 1);
        acc[g] = ai;
      }
#pragma unroll
      for (int kt = 0; kt <= 5; ++kt) {
        short8 hf = *(const short8*)(&h_lds[cur][l16][kt * 32 + lg * 8]);
#pragma unroll
        for (int g = 0; g < 4; ++g)
          acc[g] = MFMA(bv[(g * 2 + nt) * 6 + kt], hf, acc[g]);
      }
#pragma unroll
      for (int kt = 6; kt <= 7; ++kt) {
        short8 hf = *(const short8*)(&h_lds[cur][l16][kt * 32 + lg * 8]);
#pragma unroll
        for (int g = 0; g < 4; ++g)
          acc[g] = MFMA(B_lds[(w * 16 + (kt - 6) * 8 + g * 2 + nt) * 64 + l], hf, acc[g]);
      }

      float hv[4];
#pragma unroll
      for (int j = 0; j < 4; ++j) {
        float ei = ex2(acc[0][j]);
        float ef = ex2(acc[1][j]);
        float eg = ex2(acc[2][j]);
        float eo = ex2(acc[3][j]);
        float eip = 1.f + ei, egp = eg + 1.f, efp = 1.f + ef;
        float d1 = eip * egp;
        float R = rcp(d1 * efp);
        float sitg = (eg - 1.f) * efp * R;
        float cc = fmaf(c_reg[nt][j] * d1, R, sitg);
        c_reg[nt][j] = cc;
        float ec = ex2(cc * (2.f * L2E));
        float hh = (ec - 1.f) * rcp((1.f + eo) * (ec + 1.f));
        hv[j] = hh;
      }
      if (DO_HEAD) {
        hp = fmaf(hv[0], hw4[nt].x, hp); hp = fmaf(hv[1], hw4[nt].y, hp);
        hp = fmaf(hv[2], hw4[nt].z, hp); hp = fmaf(hv[3], hw4[nt].w, hp);
      }
      {
        u32x2 hwrd;
        hwrd[0] = cvtpk(hv[0], hv[1]);
        hwrd[1] = cvtpk(hv[2], hv[3]);
        *(u32x2*)(&h_lds[nxt][l16][(w * 2 + nt) * 16 + lg * 4]) = hwrd;
      }
#pragma unroll
      for (int g = 0; g < 4; ++g)
        xpf[nt][g] = *(const u32x2*)(xpb + (size_t)tn * 131072 + g * 2048 + nt * 128);
    }

    if (DO_HEAD) {
      float s = hp;
      s += __shfl_xor(s, 16);
      s += __shfl_xor(s, 32);
      if (lg == 0) headbuf[t & 1][l16][w] = s;
    }

    lgkm_barrier();

    if (DO_HEAD) {
      if (tid < 16) {
        const float* hbp = headbuf[t & 1][tid];
        float s = hbp[0] + hbp[1] + hbp[2] + hbp[3] + hbp[4] + hbp[5] + hbp[6] + hbp[7];
        out[(size_t)(b0 + tid) * 91 + (tcol0 + t)] = s + hb;
      }
    }
  }

#pragma unroll
  for (int nt = 0; nt < 2; ++nt) {
    float4 c4 = {c_reg[nt][0], c_reg[nt][1], c_reg[nt][2], c_reg[nt][3]};
    *(float4*)&c_state[(size_t)(b0 + l16) * 256 + (w * 2 + nt) * 16 + lg * 4] = c4;
  }
  for (int idx = tid; idx < 16 * 256; idx += 512)
    h_state[(size_t)(b0 + (idx >> 8)) * 256 + (idx & 255)] = h_lds[ct & 1][idx >> 8][idx & 255];
}

// ---------------------------------------------------------------------------
extern "C" void kernel_launch(void* const* d_in, const int* in_sizes, int n_in,
                              void* d_out, int out_size, void* d_ws, size_t ws_size,
                              hipStream_t stream) {
  const float* headW = (const float*)d_in[12];
  const float* headb = (const float*)d_in[13];
  float* out = (float*)d_out;
  char* ws = (char*)d_ws;

  const int T0 = in_sizes[0] / (256 * 64);
  const int T1 = in_sizes[1] / (256 * 32);
  const int T2 = in_sizes[2] / (256 * 16);
  const size_t s0 = (size_t)T0 << 19, s1 = (size_t)T1 << 19, s2 = (size_t)T2 << 19;

  if (ws_size >= s0 + s1 + s2) {
    // ---- fused path: 3 xproj into disjoint slices + 1 rec launch ----
    uint32_t* xp0 = (uint32_t*)ws;
    uint32_t* xp1 = (uint32_t*)(ws + s0);
    uint32_t* xp2 = (uint32_t*)(ws + s0 + s1);
    init_kernel<<<256, 256, 0, stream>>>((float*)ws, (uint16_t*)(ws + 262144), out);
    xproj_kernel<64><<<dim3(T0 * 2), 512, 0, stream>>>(
        (const float*)d_in[0], (const float*)d_in[3], (const float*)d_in[5], xp0, 0, T0);
    xproj_kernel<32><<<dim3(T1 * 2), 512, 0, stream>>>(
        (const float*)d_in[1], (const float*)d_in[6], (const float*)d_in[8], xp1, 0, T1);
    xproj_kernel<16><<<dim3(T2 * 2), 512, 0, stream>>>(
        (const float*)d_in[2], (const float*)d_in[9], (const float*)d_in[11], xp2, 0, T2);
    rec_fused<<<16, 512, 0, stream>>>(
        xp0, xp1, xp2, (const float*)d_in[4], (const float*)d_in[7],
        (const float*)d_in[10], out, headW, headb, T0, T1, T2);
    return;
  }

  // ---- fallback: verbatim round-8 chunked path ----
  float* c_state = (float*)ws;                      // 256 KB
  uint16_t* h_state = (uint16_t*)(ws + 262144);     // 128 KB
  uint32_t* xp = (uint32_t*)(ws + 393216);          // chunk buffer, 512 KB per t

  int ct_max = 1;
  if (ws_size > 393216 + 512 * 1024) {
    size_t c = (ws_size - 393216) / (512 * 1024);
    ct_max = (c > 365) ? 365 : (int)c;
  }

  init_kernel<<<256, 256, 0, stream>>>(c_state, h_state, out);

  struct Phase { const float* x; const float* Wih; const float* Whh; const float* b; int T; int D; int head; };
  Phase ph[3] = {
      {(const float*)d_in[0], (const float*)d_in[3], (const float*)d_in[4], (const float*)d_in[5], T0, 64, 0},
      {(const float*)d_in[1], (const float*)d_in[6], (const float*)d_in[7], (const float*)d_in[8], T1, 32, 0},
      {(const float*)d_in[2], (const float*)d_in[9], (const float*)d_in[10], (const float*)d_in[11], T2, 16, 1},
  };

  for (int pi = 0; pi < 3; ++pi) {
    const Phase& P = ph[pi];
    for (int t0 = 0; t0 < P.T; t0 += ct_max) {
      int ct = (P.T - t0 < ct_max) ? (P.T - t0) : ct_max;
      dim3 g(ct * 2);
      if (P.D == 64)
        xproj_kernel<64><<<g, 512, 0, stream>>>(P.x, P.Wih, P.b, xp, t0, P.T);
      else if (P.D == 32)
        xproj_kernel<32><<<g, 512, 0, stream>>>(P.x, P.Wih, P.b, xp, t0, P.T);
      else
        xproj_kernel<16><<<g, 512, 0, stream>>>(P.x, P.Wih, P.b, xp, t0, P.T);
      if (P.head)
        rec_kernel<1><<<16, 512, 0, stream>>>(xp, P.Whh, c_state, h_state, out,
                                              headW, headb, ct, t0);
      else
        rec_kernel<0><<<16, 512, 0, stream>>>(xp, P.Whh, c_state, h_state, out,
                                              headW, headb, ct, t0);
    }
  }
}

// Round 13
// 1324.305 us; speedup vs baseline: 1.2665x; 1.0161x over previous
//
#include <hip/hip_runtime.h>
#include <stdint.h>

// ============================================================================
// S2S2S LSTM forecaster, MI355X.  Round 13 = round-12 fusion with the R8
// schedule restored inside rec_fused:
//   (1) each phase's t-loop uses cur = t&1 (compile-time parity like R8);
//       between phases, if prev ct odd, an 8KB LDS copy resets h to buf0.
//   (2) xpf prefetch for t+1 issues right after acc-init consumes xpf
//       (issue->use window ~ full step, hides HBM latency).
// Everything else identical to round 12 (fused path + verbatim-R8 fallback).
// Output: cols 0..75 = future-decoder head, 76..90 = 0 (ref overwrites out_f).
// ============================================================================

typedef __attribute__((ext_vector_type(8))) short short8;  // 8 x bf16
typedef __attribute__((ext_vector_type(4))) float f32x4;   // MFMA acc
typedef __attribute__((ext_vector_type(2))) unsigned int u32x2;
typedef __attribute__((ext_vector_type(4))) unsigned int u32x4;

#define L2E 1.4426950408889634f

__device__ __forceinline__ uint16_t f2bf(float f) {  // fp32 -> bf16 bits, RNE
  uint32_t x = __float_as_uint(f);
  x += 0x7fffu + ((x >> 16) & 1u);
  return (uint16_t)(x >> 16);
}
__device__ __forceinline__ uint32_t cvtpk(float lo, float hi) {  // 1-inst pack
  uint32_t r;
  asm("v_cvt_pk_bf16_f32 %0, %1, %2" : "=v"(r) : "v"(lo), "v"(hi));
  return r;
}
__device__ __forceinline__ float bfhalf(uint32_t w, int hi) {  // bf16 -> fp32
  return __uint_as_float(hi ? (w & 0xffff0000u) : (w << 16));
}
__device__ __forceinline__ f32x4 MFMA(short8 a, short8 b, f32x4 c) {
  return __builtin_amdgcn_mfma_f32_16x16x32_bf16(a, b, c, 0, 0, 0);
}
__device__ __forceinline__ float ex2(float x) { return __builtin_amdgcn_exp2f(x); }
__device__ __forceinline__ float rcp(float x) { return __builtin_amdgcn_rcpf(x); }

// pack 8 consecutive floats (16B-aligned) * scale -> short8 of bf16
__device__ __forceinline__ short8 pack8s(const float* s, float sc) {
  float4 q0 = *(const float4*)s, q1 = *(const float4*)(s + 4);
  u32x4 t;
  t[0] = cvtpk(q0.x * sc, q0.y * sc);
  t[1] = cvtpk(q0.z * sc, q0.w * sc);
  t[2] = cvtpk(q1.x * sc, q1.y * sc);
  t[3] = cvtpk(q1.z * sc, q1.w * sc);
  return *(short8*)&t;
}

// Barrier waiting only LDS ops (lgkmcnt), NOT vmcnt: xp prefetch loads stay
// in flight across steps. sched_barriers fence code motion.
__device__ __forceinline__ void lgkm_barrier() {
  __builtin_amdgcn_sched_barrier(0);
  asm volatile("s_waitcnt lgkmcnt(0)" ::: "memory");
  __builtin_amdgcn_s_barrier();
  __builtin_amdgcn_sched_barrier(0);
}

// ---------------------------------------------------------------------------
__global__ void init_kernel(float* c_state, uint16_t* h_state, float* out,
                            int full) {
  int i = blockIdx.x * 256 + threadIdx.x;
  if (full && i < 65536) { c_state[i] = 0.f; h_state[i] = 0; }
  if (i < 256 * 91) out[i] = 0.f;
}

// ---------------------------------------------------------------------------
// xproj: transposed, pre-scaled C^T fragments,
// xp[tc][btile][rowtile][lane][2], value = (x@Wih^T+b)*(g? +2log2e : -log2e).
// ---------------------------------------------------------------------------
template <int DIN>
__global__ __launch_bounds__(512) void xproj_kernel(
    const float* __restrict__ x, const float* __restrict__ Wih,
    const float* __restrict__ bias, uint32_t* __restrict__ xp,
    int t0, int T) {
  const int tid = threadIdx.x, w = tid >> 6, l = tid & 63;
  const int l16 = l & 15, lg = l >> 4;
  const int tc = blockIdx.x >> 1;
  const int sub = blockIdx.x & 1;
  const int t = t0 + tc;
  constexpr int KT = (DIN + 31) / 32;

  short8 bfr[8][KT];
  float4 bias4[8];
#pragma unroll
  for (int ni = 0; ni < 8; ++ni) {
    const int n = (w * 8 + ni) * 16 + l16;
    bias4[ni] = *(const float4*)&bias[(w * 8 + ni) * 16 + lg * 4];
#pragma unroll
    for (int kt = 0; kt < KT; ++kt) {
      const int k0 = kt * 32 + lg * 8;
      short8 fr;
#pragma unroll
      for (int e = 0; e < 8; ++e) fr[e] = 0;
      if (k0 + 8 <= DIN) fr = pack8s(Wih + (size_t)n * DIN + k0, 1.f);
      bfr[ni][kt] = fr;
    }
  }

  for (int mi = 0; mi < 8; ++mi) {
    const int btile = sub * 8 + mi;
    const int b = btile * 16 + l16;
    short8 af[KT];
#pragma unroll
    for (int kt = 0; kt < KT; ++kt) {
      const int k0 = kt * 32 + lg * 8;
      short8 fr;
#pragma unroll
      for (int e = 0; e < 8; ++e) fr[e] = 0;
      if (k0 + 8 <= DIN) fr = pack8s(x + ((size_t)b * T + t) * DIN + k0, 1.f);
      af[kt] = fr;
    }
#pragma unroll
    for (int ni = 0; ni < 8; ++ni) {
      f32x4 acc = {0.f, 0.f, 0.f, 0.f};
#pragma unroll
      for (int kt = 0; kt < KT; ++kt) acc = MFMA(bfr[ni][kt], af[kt], acc);
      const int nt = w * 8 + ni;
      const float sc = ((nt >> 4) == 2) ? (2.f * L2E) : -L2E;
      size_t idx = ((((size_t)tc * 16 + btile) * 64 + nt) * 64 + l) * 2;
      u32x2 v;
      v[0] = cvtpk((acc[0] + bias4[ni].x) * sc, (acc[1] + bias4[ni].y) * sc);
      v[1] = cvtpk((acc[2] + bias4[ni].z) * sc, (acc[3] + bias4[ni].w) * sc);
      *(u32x2*)(xp + idx) = v;
    }
  }
}

// ---------------------------------------------------------------------------
// rec_fused: 16 blocks x 512 thr; all 3 phases in one launch, R8 inner loop.
// Wave w owns hidden cols [32w,32w+32) (2 row-tiles nt), all 4 gates.
// Whh frags PRE-SCALED; kt<=5 -> bv[(g*2+nt)*6+kt]; kt6,7 -> B_lds.
// Per phase: t-loop with cur = t&1 (R8 form); if ct odd, h copied buf1->buf0
// before the next phase. xpf prefetch issues right after acc init (early).
// ---------------------------------------------------------------------------
__global__ __launch_bounds__(512, 2) void rec_fused(
    const uint32_t* __restrict__ xp0, const uint32_t* __restrict__ xp1,
    const uint32_t* __restrict__ xp2, const float* __restrict__ Whh0,
    const float* __restrict__ Whh1, const float* __restrict__ Whh2,
    float* __restrict__ out, const float* __restrict__ headW,
    const float* __restrict__ headb, int T0, int T1, int T2) {
  __shared__ short8 B_lds[8 * 16 * 64];   // 131072 B
  __shared__ uint16_t h_lds[2][16][264];  // 16896 B (double-buffered, pad 264)
  __shared__ float headbuf[2][16][8];     // 1024 B

  const int tid = threadIdx.x, w = tid >> 6, l = tid & 63;
  const int l16 = l & 15, lg = l >> 4;
  const int blk = blockIdx.x, b0 = blk * 16;

  // ---- zero initial state (h in LDS buf 0, c in regs) ----
  float c_reg[2][4];
#pragma unroll
  for (int nt = 0; nt < 2; ++nt)
#pragma unroll
    for (int j = 0; j < 4; ++j) c_reg[nt][j] = 0.f;
  for (int idx = tid; idx < 16 * 264; idx += 512)
    ((uint16_t*)h_lds)[idx] = 0;   // h_lds[0] flat
  float4 hw4[2];
#pragma unroll
  for (int nt = 0; nt < 2; ++nt)
    hw4[nt] = *(const float4*)&headW[(w * 2 + nt) * 16 + lg * 4];
  const float hb = headb[0];

  for (int p = 0; p < 3; ++p) {
    const float* Whh = (p == 0) ? Whh0 : (p == 1) ? Whh1 : Whh2;
    const uint32_t* xp = (p == 0) ? xp0 : (p == 1) ? xp1 : xp2;
    const int ct = (p == 0) ? T0 : (p == 1) ? T1 : T2;
    const bool headf = (p == 2);

    // ---- Whh -> prescaled bf16 fragments: regs (kt0..5) / LDS (kt6,7) ----
    short8 bv[48];
#pragma unroll
    for (int g = 0; g < 4; ++g) {
      const float wsc = (g == 2) ? (2.f * L2E) : -L2E;  // gate order i,f,g,o
#pragma unroll
      for (int nt = 0; nt < 2; ++nt)
#pragma unroll
        for (int kt = 0; kt < 8; ++kt) {
          const int row = (g * 16 + w * 2 + nt) * 16 + l16;
          short8 fr = pack8s(Whh + (size_t)row * 256 + kt * 32 + lg * 8, wsc);
          const int tile = g * 2 + nt;
          if (kt <= 5) bv[tile * 6 + kt] = fr;
          else B_lds[(w * 16 + (kt - 6) * 8 + tile) * 64 + l] = fr;
        }
    }

    // ---- xp prefetch for t=0 of this phase ----
    const uint32_t* xpb = xp + ((size_t)(blk * 64 + w * 2) * 64 + l) * 2;
    u32x2 xpf[2][4];
#pragma unroll
    for (int nt = 0; nt < 2; ++nt)
#pragma unroll
      for (int g = 0; g < 4; ++g)
        xpf[nt][g] = *(const u32x2*)(xpb + (size_t)g * 2048 + nt * 128);

    __syncthreads();

    for (int t = 0; t < ct; ++t) {
      const int cur = t & 1, nxt = cur ^ 1;          // R8 form
      const int tn = (t + 1 < ct) ? t + 1 : t;
      float hp = 0.f;

#pragma unroll
      for (int nt = 0; nt < 2; ++nt) {
        // ---- acc init from prescaled xp (srcC), consumes xpf ----
        f32x4 acc[4];
#pragma unroll
        for (int g = 0; g < 4; ++g) {
          f32x4 ai;
          ai[0] = bfhalf(xpf[nt][g][0], 0);
          ai[1] = bfhalf(xpf[nt][g][0], 1);
          ai[2] = bfhalf(xpf[nt][g][1], 0);
          ai[3] = bfhalf(xpf[nt][g][1], 1);
          acc[g] = ai;
        }
        // ---- EARLY prefetch of next step's xp (full-step window) ----
#pragma unroll
        for (int g = 0; g < 4; ++g)
          xpf[nt][g] = *(const u32x2*)(xpb + (size_t)tn * 131072 + g * 2048 + nt * 128);
        // ---- 8-kt MFMA chain ----
#pragma unroll
        for (int kt = 0; kt <= 5; ++kt) {
          short8 hf = *(const short8*)(&h_lds[cur][l16][kt * 32 + lg * 8]);
#pragma unroll
          for (int g = 0; g < 4; ++g)
            acc[g] = MFMA(bv[(g * 2 + nt) * 6 + kt], hf, acc[g]);
        }
#pragma unroll
        for (int kt = 6; kt <= 7; ++kt) {
          short8 hf = *(const short8*)(&h_lds[cur][l16][kt * 32 + lg * 8]);
#pragma unroll
          for (int g = 0; g < 4; ++g)
            acc[g] = MFMA(B_lds[(w * 16 + (kt - 6) * 8 + g * 2 + nt) * 64 + l], hf, acc[g]);
        }

        // ---- activations: acc[g][j] = scaled gate arg; i,f,g,o ----
        float hv[4];
#pragma unroll
        for (int j = 0; j < 4; ++j) {
          float ei = ex2(acc[0][j]);            // e^{-I}
          float ef = ex2(acc[1][j]);            // e^{-F}
          float eg = ex2(acc[2][j]);            // e^{+2G}
          float eo = ex2(acc[3][j]);            // e^{-O}
          float eip = 1.f + ei, egp = eg + 1.f, efp = 1.f + ef;
          float d1 = eip * egp;
          float R = rcp(d1 * efp);              // 1/((1+ei)(eg+1)(1+ef))
          float sitg = (eg - 1.f) * efp * R;    // sig(I)tanh(G)
          float cc = fmaf(c_reg[nt][j] * d1, R, sitg);  // + sig(F)*c
          c_reg[nt][j] = cc;
          float ec = ex2(cc * (2.f * L2E));     // e^{2c}
          float hh = (ec - 1.f) * rcp((1.f + eo) * (ec + 1.f));
          hv[j] = hh;
        }
        if (headf) {
          hp = fmaf(hv[0], hw4[nt].x, hp); hp = fmaf(hv[1], hw4[nt].y, hp);
          hp = fmaf(hv[2], hw4[nt].z, hp); hp = fmaf(hv[3], hw4[nt].w, hp);
        }
        // packed h write: 4 contiguous bf16 cols -> one b64 store
        {
          u32x2 hwrd;
          hwrd[0] = cvtpk(hv[0], hv[1]);
          hwrd[1] = cvtpk(hv[2], hv[3]);
          *(u32x2*)(&h_lds[nxt][l16][(w * 2 + nt) * 16 + lg * 4]) = hwrd;
        }
      }

      if (headf) {
        float s = hp;
        s += __shfl_xor(s, 16);
        s += __shfl_xor(s, 32);
        if (lg == 0) headbuf[t & 1][l16][w] = s;
      }

      lgkm_barrier();  // h[nxt] (and headbuf) visible; all cur-reads done

      if (headf) {
        if (tid < 16) {
          const float* hbp = headbuf[t & 1][tid];
          float s = hbp[0] + hbp[1] + hbp[2] + hbp[3] + hbp[4] + hbp[5] + hbp[6] + hbp[7];
          out[(size_t)(b0 + tid) * 91 + t] = s + hb;
        }
      }
    }

    // ---- parity reset: next phase expects h in buf0 ----
    if (p < 2 && (ct & 1)) {
      // copy h_lds[1][r][0..255] -> h_lds[0][r][0..255] (vectorized)
      for (int idx = tid; idx < 1024; idx += 512) {
        const int r = idx >> 6, c4 = (idx & 63) * 4;
        *(u32x2*)(&h_lds[0][r][c4]) = *(const u32x2*)(&h_lds[1][r][c4]);
      }
      // visibility handled by next phase's __syncthreads (after frag load)
    }
  }
}

// ---------------------------------------------------------------------------
// Fallback rec kernel: verbatim round 8 (chunked path, proven).
// ---------------------------------------------------------------------------
template <int DO_HEAD>
__global__ __launch_bounds__(512, 2) void rec_kernel(
    const uint32_t* __restrict__ xp, const float* __restrict__ Whh,
    float* __restrict__ c_state, uint16_t* __restrict__ h_state,
    float* __restrict__ out, const float* __restrict__ headW,
    const float* __restrict__ headb, int ct, int tcol0) {
  __shared__ short8 B_lds[8 * 16 * 64];
  __shared__ uint16_t h_lds[2][16][264];
  __shared__ float headbuf[2][16][8];

  const int tid = threadIdx.x, w = tid >> 6, l = tid & 63;
  const int l16 = l & 15, lg = l >> 4;
  const int blk = blockIdx.x, b0 = blk * 16;

  short8 bv[48];
#pragma unroll
  for (int g = 0; g < 4; ++g) {
    const float wsc = (g == 2) ? (2.f * L2E) : -L2E;
#pragma unroll
    for (int nt = 0; nt < 2; ++nt)
#pragma unroll
      for (int kt = 0; kt < 8; ++kt) {
        const int row = (g * 16 + w * 2 + nt) * 16 + l16;
        const float* s = Whh + (size_t)row * 256 + kt * 32 + lg * 8;
        short8 fr;
#pragma unroll
        for (int e = 0; e < 8; ++e) fr[e] = (short)f2bf(s[e] * wsc);
        const int tile = g * 2 + nt;
        if (kt <= 5) bv[tile * 6 + kt] = fr;
        else B_lds[(w * 16 + (kt - 6) * 8 + tile) * 64 + l] = fr;
      }
  }

  float c_reg[2][4];
#pragma unroll
  for (int nt = 0; nt < 2; ++nt) {
    float4 c4 = *(const float4*)&c_state[(size_t)(b0 + l16) * 256 +
                                         (w * 2 + nt) * 16 + lg * 4];
    c_reg[nt][0] = c4.x; c_reg[nt][1] = c4.y;
    c_reg[nt][2] = c4.z; c_reg[nt][3] = c4.w;
  }
  for (int idx = tid; idx < 16 * 256; idx += 512)
    h_lds[0][idx >> 8][idx & 255] = h_state[(size_t)(b0 + (idx >> 8)) * 256 + (idx & 255)];
  float4 hw4[2];
#pragma unroll
  for (int nt = 0; nt < 2; ++nt)
    hw4[nt] = *(const float4*)&headW[(w * 2 + nt) * 16 + lg * 4];
  const float hb = headb[0];

  const uint32_t* xpb = xp + ((size_t)(blk * 64 + w * 2) * 64 + l) * 2;
  u32x2 xpf[2][4];
#pragma unroll
  for (int nt = 0; nt < 2; ++nt)
#pragma unroll
    for (int g = 0; g < 4; ++g)
      xpf[nt][g] = *(const u32x2*)(xpb + (size_t)g * 2048 + nt * 128);

  __syncthreads();

  for (int t = 0; t < ct; ++t) {
    const int cur = t & 1, nxt = cur ^ 1;
    const int tn = (t + 1 < ct) ? t + 1 : t;
    float hp = 0.f;

#pragma unroll
    for (int nt = 0; nt < 2; ++nt) {
      f32x4 acc[4];
#pragma unroll
      for (int g = 0; g < 4; ++g) {
        f32x4 ai;
        ai[0] = bfhalf(xpf[nt][g][0], 0);
        ai[1] = bfhalf(xpf[nt][g][0], 1);
        ai[2] = bfhalf(xpf[nt][g][1], 0);
        ai[3] = bfhalf(xpf[nt][g][1], 1);
        acc[g] = ai;
      }
#pragma unroll
      for (int kt = 0; kt <= 5; ++kt) {
        short8 hf = *(const short8*)(&h_lds[cur][l16][kt * 32 + lg * 8]);
#pragma unroll
        for (int g = 0; g < 4; ++g)
          acc[g] = MFMA(bv[(g * 2 + nt) * 6 + kt], hf, acc[g]);
      }
#pragma unroll
      for (int kt = 6; kt <= 7; ++kt) {
        short8 hf = *(const short8*)(&h_lds[cur][l16][kt * 32 + lg * 8]);
#pragma unroll
        for (int g = 0; g < 4; ++g)
          acc[g] = MFMA(B_lds[(w * 16 + (kt - 6) * 8 + g * 2 + nt) * 64 + l], hf, acc[g]);
      }

      float hv[4];
#pragma unroll
      for (int j = 0; j < 4; ++j) {
        float ei = ex2(acc[0][j]);
        float ef = ex2(acc[1][j]);
        float eg = ex2(acc[2][j]);
        float eo = ex2(acc[3][j]);
        float eip = 1.f + ei, egp = eg + 1.f, efp = 1.f + ef;
        float d1 = eip * egp;
        float R = rcp(d1 * efp);
        float sitg = (eg - 1.f) * efp * R;
        float cc = fmaf(c_reg[nt][j] * d1, R, sitg);
        c_reg[nt][j] = cc;
        float ec = ex2(cc * (2.f * L2E));
        float hh = (ec - 1.f) * rcp((1.f + eo) * (ec + 1.f));
        hv[j] = hh;
      }
      if (DO_HEAD) {
        hp = fmaf(hv[0], hw4[nt].x, hp); hp = fmaf(hv[1], hw4[nt].y, hp);
        hp = fmaf(hv[2], hw4[nt].z, hp); hp = fmaf(hv[3], hw4[nt].w, hp);
      }
      {
        u32x2 hwrd;
        hwrd[0] = cvtpk(hv[0], hv[1]);
        hwrd[1] = cvtpk(hv[2], hv[3]);
        *(u32x2*)(&h_lds[nxt][l16][(w * 2 + nt) * 16 + lg * 4]) = hwrd;
      }
#pragma unroll
      for (int g = 0; g < 4; ++g)
        xpf[nt][g] = *(const u32x2*)(xpb + (size_t)tn * 131072 + g * 2048 + nt * 128);
    }

    if (DO_HEAD) {
      float s = hp;
      s += __shfl_xor(s, 16);
      s += __shfl_xor(s, 32);
      if (lg == 0) headbuf[t & 1][l16][w] = s;
    }

    lgkm_barrier();

    if (DO_HEAD) {
      if (tid < 16) {
        const float* hbp = headbuf[t & 1][tid];
        float s = hbp[0] + hbp[1] + hbp[2] + hbp[3] + hbp[4] + hbp[5] + hbp[6] + hbp[7];
        out[(size_t)(b0 + tid) * 91 + (tcol0 + t)] = s + hb;
      }
    }
  }

#pragma unroll
  for (int nt = 0; nt < 2; ++nt) {
    float4 c4 = {c_reg[nt][0], c_reg[nt][1], c_reg[nt][2], c_reg[nt][3]};
    *(float4*)&c_state[(size_t)(b0 + l16) * 256 + (w * 2 + nt) * 16 + lg * 4] = c4;
  }
  for (int idx = tid; idx < 16 * 256; idx += 512)
    h_state[(size_t)(b0 + (idx >> 8)) * 256 + (idx & 255)] = h_lds[ct & 1][idx >> 8][idx & 255];
}

// ---------------------------------------------------------------------------
extern "C" void kernel_launch(void* const* d_in, const int* in_sizes, int n_in,
                              void* d_out, int out_size, void* d_ws, size_t ws_size,
                              hipStream_t stream) {
  const float* headW = (const float*)d_in[12];
  const float* headb = (const float*)d_in[13];
  float* out = (float*)d_out;
  char* ws = (char*)d_ws;

  const int T0 = in_sizes[0] / (256 * 64);
  const int T1 = in_sizes[1] / (256 * 32);
  const int T2 = in_sizes[2] / (256 * 16);
  const size_t s0 = (size_t)T0 << 19, s1 = (size_t)T1 << 19, s2 = (size_t)T2 << 19;

  if (ws_size >= s0 + s1 + s2) {
    // ---- fused path: 3 xproj into disjoint slices + 1 rec launch ----
    uint32_t* xp0 = (uint32_t*)ws;
    uint32_t* xp1 = (uint32_t*)(ws + s0);
    uint32_t* xp2 = (uint32_t*)(ws + s0 + s1);
    init_kernel<<<256, 256, 0, stream>>>(nullptr, nullptr, out, 0);
    xproj_kernel<64><<<dim3(T0 * 2), 512, 0, stream>>>(
        (const float*)d_in[0], (const float*)d_in[3], (const float*)d_in[5], xp0, 0, T0);
    xproj_kernel<32><<<dim3(T1 * 2), 512, 0, stream>>>(
        (const float*)d_in[1], (const float*)d_in[6], (const float*)d_in[8], xp1, 0, T1);
    xproj_kernel<16><<<dim3(T2 * 2), 512, 0, stream>>>(
        (const float*)d_in[2], (const float*)d_in[9], (const float*)d_in[11], xp2, 0, T2);
    rec_fused<<<16, 512, 0, stream>>>(
        xp0, xp1, xp2, (const float*)d_in[4], (const float*)d_in[7],
        (const float*)d_in[10], out, headW, headb, T0, T1, T2);
    return;
  }

  // ---- fallback: verbatim round-8 chunked path ----
  float* c_state = (float*)ws;                      // 256 KB
  uint16_t* h_state = (uint16_t*)(ws + 262144);     // 128 KB
  uint32_t* xp = (uint32_t*)(ws + 393216);          // chunk buffer, 512 KB per t

  int ct_max = 1;
  if (ws_size > 393216 + 512 * 1024) {
    size_t c = (ws_size - 393216) / (512 * 1024);
    ct_max = (c > 365) ? 365 : (int)c;
  }

  init_kernel<<<256, 256, 0, stream>>>(c_state, h_state, out, 1);

  struct Phase { const float* x; const float* Wih; const float* Whh; const float* b; int T; int D; int head; };
  Phase ph[3] = {
      {(const float*)d_in[0], (const float*)d_in[3], (const float*)d_in[4], (const float*)d_in[5], T0, 64, 0},
      {(const float*)d_in[1], (const float*)d_in[6], (const float*)d_in[7], (const float*)d_in[8], T1, 32, 0},
      {(const float*)d_in[2], (const float*)d_in[9], (const float*)d_in[10], (const float*)d_in[11], T2, 16, 1},
  };

  for (int pi = 0; pi < 3; ++pi) {
    const Phase& P = ph[pi];
    for (int t0 = 0; t0 < P.T; t0 += ct_max) {
      int ct = (P.T - t0 < ct_max) ? (P.T - t0) : ct_max;
      dim3 g(ct * 2);
      if (P.D == 64)
        xproj_kernel<64><<<g, 512, 0, stream>>>(P.x, P.Wih, P.b, xp, t0, P.T);
      else if (P.D == 32)
        xproj_kernel<32><<<g, 512, 0, stream>>>(P.x, P.Wih, P.b, xp, t0, P.T);
      else
        xproj_kernel<16><<<g, 512, 0, stream>>>(P.x, P.Wih, P.b, xp, t0, P.T);
      if (P.head)
        rec_kernel<1><<<16, 512, 0, stream>>>(xp, P.Whh, c_state, h_state, out,
                                              headW, headb, ct, t0);
      else
        rec_kernel<0><<<16, 512, 0, stream>>>(xp, P.Whh, c_state, h_state, out,
                                              headW, headb, ct, t0);
    }
  }
}

// Round 14
// 1242.522 us; speedup vs baseline: 1.3499x; 1.0658x over previous
//
#include <hip/hip_runtime.h>
#include <stdint.h>

// ============================================================================
// S2S2S LSTM forecaster, MI355X.  Round 14: best-of assembly, proven pieces.
//   - encoder: R8's 16-block rec_kernel (verbatim; 822us, 85% issue-occ)
//   - decoders: R10's 32-block split rec (verbatim; ~1.8us/step incl. phase2
//     deferred-exchange head protocol) -- state layouts bit-compatible
//   - all 3 xproj launches first (disjoint xp slices), rec dispatches
//     back-to-back to shrink launch gaps
//   - fallback: R8 chunked path (proven) if ws too small
// Output: cols 0..75 = future-decoder head, 76..90 = 0 (ref overwrites out_f).
// ============================================================================

typedef __attribute__((ext_vector_type(8))) short short8;  // 8 x bf16
typedef __attribute__((ext_vector_type(4))) float f32x4;   // MFMA acc
typedef __attribute__((ext_vector_type(2))) unsigned int u32x2;
typedef __attribute__((ext_vector_type(4))) unsigned int u32x4;

#define L2E 1.4426950408889634f

__device__ __forceinline__ uint16_t f2bf(float f) {  // fp32 -> bf16 bits, RNE
  uint32_t x = __float_as_uint(f);
  x += 0x7fffu + ((x >> 16) & 1u);
  return (uint16_t)(x >> 16);
}
__device__ __forceinline__ uint32_t cvtpk(float lo, float hi) {  // 1-inst pack
  uint32_t r;
  asm("v_cvt_pk_bf16_f32 %0, %1, %2" : "=v"(r) : "v"(lo), "v"(hi));
  return r;
}
__device__ __forceinline__ float bfhalf(uint32_t w, int hi) {  // bf16 -> fp32
  return __uint_as_float(hi ? (w & 0xffff0000u) : (w << 16));
}
__device__ __forceinline__ f32x4 MFMA(short8 a, short8 b, f32x4 c) {
  return __builtin_amdgcn_mfma_f32_16x16x32_bf16(a, b, c, 0, 0, 0);
}
__device__ __forceinline__ float ex2(float x) { return __builtin_amdgcn_exp2f(x); }
__device__ __forceinline__ float rcp(float x) { return __builtin_amdgcn_rcpf(x); }

// pack 8 consecutive floats (16B-aligned) * scale -> short8 of bf16
__device__ __forceinline__ short8 pack8s(const float* s, float sc) {
  float4 q0 = *(const float4*)s, q1 = *(const float4*)(s + 4);
  u32x4 t;
  t[0] = cvtpk(q0.x * sc, q0.y * sc);
  t[1] = cvtpk(q0.z * sc, q0.w * sc);
  t[2] = cvtpk(q1.x * sc, q1.y * sc);
  t[3] = cvtpk(q1.z * sc, q1.w * sc);
  return *(short8*)&t;
}

// Barrier waiting only LDS ops (lgkmcnt), NOT vmcnt.
__device__ __forceinline__ void lgkm_barrier() {
  __builtin_amdgcn_sched_barrier(0);
  asm volatile("s_waitcnt lgkmcnt(0)" ::: "memory");
  __builtin_amdgcn_s_barrier();
  __builtin_amdgcn_sched_barrier(0);
}
// drain oldest vmem ops but keep 4 xp prefetch loads in flight
__device__ __forceinline__ void vm_drain4() {
  __builtin_amdgcn_sched_barrier(0);
  asm volatile("s_waitcnt vmcnt(4)" ::: "memory");
  __builtin_amdgcn_sched_barrier(0);
}

// ---------------------------------------------------------------------------
__global__ void init_kernel(float* c_state, uint16_t* h_state, float* out,
                            uint32_t* flags) {
  int i = blockIdx.x * 256 + threadIdx.x;
  if (i < 65536) { c_state[i] = 0.f; h_state[i] = 0; }
  if (i < 256 * 91) out[i] = 0.f;
  if (flags && i < 96) flags[i] = 0;   // 3 phases x 16 pairs x 2 subs
}

// ---------------------------------------------------------------------------
// xproj: transposed, pre-scaled C^T fragments,
// xp[tc][btile][rowtile][lane][2], value = (x@Wih^T+b)*(g? +2log2e : -log2e).
// ---------------------------------------------------------------------------
template <int DIN>
__global__ __launch_bounds__(512) void xproj_kernel(
    const float* __restrict__ x, const float* __restrict__ Wih,
    const float* __restrict__ bias, uint32_t* __restrict__ xp,
    int t0, int T) {
  const int tid = threadIdx.x, w = tid >> 6, l = tid & 63;
  const int l16 = l & 15, lg = l >> 4;
  const int tc = blockIdx.x >> 1;
  const int sub = blockIdx.x & 1;
  const int t = t0 + tc;
  constexpr int KT = (DIN + 31) / 32;

  short8 bfr[8][KT];
  float4 bias4[8];
#pragma unroll
  for (int ni = 0; ni < 8; ++ni) {
    const int n = (w * 8 + ni) * 16 + l16;
    bias4[ni] = *(const float4*)&bias[(w * 8 + ni) * 16 + lg * 4];
#pragma unroll
    for (int kt = 0; kt < KT; ++kt) {
      const int k0 = kt * 32 + lg * 8;
      short8 fr;
#pragma unroll
      for (int e = 0; e < 8; ++e) fr[e] = 0;
      if (k0 + 8 <= DIN) fr = pack8s(Wih + (size_t)n * DIN + k0, 1.f);
      bfr[ni][kt] = fr;
    }
  }

  for (int mi = 0; mi < 8; ++mi) {
    const int btile = sub * 8 + mi;
    const int b = btile * 16 + l16;
    short8 af[KT];
#pragma unroll
    for (int kt = 0; kt < KT; ++kt) {
      const int k0 = kt * 32 + lg * 8;
      short8 fr;
#pragma unroll
      for (int e = 0; e < 8; ++e) fr[e] = 0;
      if (k0 + 8 <= DIN) fr = pack8s(x + ((size_t)b * T + t) * DIN + k0, 1.f);
      af[kt] = fr;
    }
#pragma unroll
    for (int ni = 0; ni < 8; ++ni) {
      f32x4 acc = {0.f, 0.f, 0.f, 0.f};
#pragma unroll
      for (int kt = 0; kt < KT; ++kt) acc = MFMA(bfr[ni][kt], af[kt], acc);
      const int nt = w * 8 + ni;
      const float sc = ((nt >> 4) == 2) ? (2.f * L2E) : -L2E;
      size_t idx = ((((size_t)tc * 16 + btile) * 64 + nt) * 64 + l) * 2;
      u32x2 v;
      v[0] = cvtpk((acc[0] + bias4[ni].x) * sc, (acc[1] + bias4[ni].y) * sc);
      v[1] = cvtpk((acc[2] + bias4[ni].z) * sc, (acc[3] + bias4[ni].w) * sc);
      *(u32x2*)(xp + idx) = v;
    }
  }
}

// ---------------------------------------------------------------------------
// R8 rec_kernel (verbatim): 16 blocks x 512 thr.
// ---------------------------------------------------------------------------
template <int DO_HEAD>
__global__ __launch_bounds__(512, 2) void rec_kernel(
    const uint32_t* __restrict__ xp, const float* __restrict__ Whh,
    float* __restrict__ c_state, uint16_t* __restrict__ h_state,
    float* __restrict__ out, const float* __restrict__ headW,
    const float* __restrict__ headb, int ct, int tcol0) {
  __shared__ short8 B_lds[8 * 16 * 64];
  __shared__ uint16_t h_lds[2][16][264];
  __shared__ float headbuf[2][16][8];

  const int tid = threadIdx.x, w = tid >> 6, l = tid & 63;
  const int l16 = l & 15, lg = l >> 4;
  const int blk = blockIdx.x, b0 = blk * 16;

  short8 bv[48];
#pragma unroll
  for (int g = 0; g < 4; ++g) {
    const float wsc = (g == 2) ? (2.f * L2E) : -L2E;
#pragma unroll
    for (int nt = 0; nt < 2; ++nt)
#pragma unroll
      for (int kt = 0; kt < 8; ++kt) {
        const int row = (g * 16 + w * 2 + nt) * 16 + l16;
        const float* s = Whh + (size_t)row * 256 + kt * 32 + lg * 8;
        short8 fr;
#pragma unroll
        for (int e = 0; e < 8; ++e) fr[e] = (short)f2bf(s[e] * wsc);
        const int tile = g * 2 + nt;
        if (kt <= 5) bv[tile * 6 + kt] = fr;
        else B_lds[(w * 16 + (kt - 6) * 8 + tile) * 64 + l] = fr;
      }
  }

  float c_reg[2][4];
#pragma unroll
  for (int nt = 0; nt < 2; ++nt) {
    float4 c4 = *(const float4*)&c_state[(size_t)(b0 + l16) * 256 +
                                         (w * 2 + nt) * 16 + lg * 4];
    c_reg[nt][0] = c4.x; c_reg[nt][1] = c4.y;
    c_reg[nt][2] = c4.z; c_reg[nt][3] = c4.w;
  }
  for (int idx = tid; idx < 16 * 256; idx += 512)
    h_lds[0][idx >> 8][idx & 255] = h_state[(size_t)(b0 + (idx >> 8)) * 256 + (idx & 255)];
  float4 hw4[2];
#pragma unroll
  for (int nt = 0; nt < 2; ++nt)
    hw4[nt] = *(const float4*)&headW[(w * 2 + nt) * 16 + lg * 4];
  const float hb = headb[0];

  const uint32_t* xpb = xp + ((size_t)(blk * 64 + w * 2) * 64 + l) * 2;
  u32x2 xpf[2][4];
#pragma unroll
  for (int nt = 0; nt < 2; ++nt)
#pragma unroll
    for (int g = 0; g < 4; ++g)
      xpf[nt][g] = *(const u32x2*)(xpb + (size_t)g * 2048 + nt * 128);

  __syncthreads();

  for (int t = 0; t < ct; ++t) {
    const int cur = t & 1, nxt = cur ^ 1;
    const int tn = (t + 1 < ct) ? t + 1 : t;
    float hp = 0.f;

#pragma unroll
    for (int nt = 0; nt < 2; ++nt) {
      f32x4 acc[4];
#pragma unroll
      for (int g = 0; g < 4; ++g) {
        f32x4 ai;
        ai[0] = bfhalf(xpf[nt][g][0], 0);
        ai[1] = bfhalf(xpf[nt][g][0], 1);
        ai[2] = bfhalf(xpf[nt][g][1], 0);
        ai[3] = bfhalf(xpf[nt][g][1], 1);
        acc[g] = ai;
      }
#pragma unroll
      for (int kt = 0; kt <= 5; ++kt) {
        short8 hf = *(const short8*)(&h_lds[cur][l16][kt * 32 + lg * 8]);
#pragma unroll
        for (int g = 0; g < 4; ++g)
          acc[g] = MFMA(bv[(g * 2 + nt) * 6 + kt], hf, acc[g]);
      }
#pragma unroll
      for (int kt = 6; kt <= 7; ++kt) {
        short8 hf = *(const short8*)(&h_lds[cur][l16][kt * 32 + lg * 8]);
#pragma unroll
        for (int g = 0; g < 4; ++g)
          acc[g] = MFMA(B_lds[(w * 16 + (kt - 6) * 8 + g * 2 + nt) * 64 + l], hf, acc[g]);
      }

      float hv[4];
#pragma unroll
      for (int j = 0; j < 4; ++j) {
        float ei = ex2(acc[0][j]);
        float ef = ex2(acc[1][j]);
        float eg = ex2(acc[2][j]);
        float eo = ex2(acc[3][j]);
        float eip = 1.f + ei, egp = eg + 1.f, efp = 1.f + ef;
        float d1 = eip * egp;
        float R = rcp(d1 * efp);
        float sitg = (eg - 1.f) * efp * R;
        float cc = fmaf(c_reg[nt][j] * d1, R, sitg);
        c_reg[nt][j] = cc;
        float ec = ex2(cc * (2.f * L2E));
        float hh = (ec - 1.f) * rcp((1.f + eo) * (ec + 1.f));
        hv[j] = hh;
      }
      if (DO_HEAD) {
        hp = fmaf(hv[0], hw4[nt].x, hp); hp = fmaf(hv[1], hw4[nt].y, hp);
        hp = fmaf(hv[2], hw4[nt].z, hp); hp = fmaf(hv[3], hw4[nt].w, hp);
      }
      {
        u32x2 hwrd;
        hwrd[0] = cvtpk(hv[0], hv[1]);
        hwrd[1] = cvtpk(hv[2], hv[3]);
        *(u32x2*)(&h_lds[nxt][l16][(w * 2 + nt) * 16 + lg * 4]) = hwrd;
      }
#pragma unroll
      for (int g = 0; g < 4; ++g)
        xpf[nt][g] = *(const u32x2*)(xpb + (size_t)tn * 131072 + g * 2048 + nt * 128);
    }

    if (DO_HEAD) {
      float s = hp;
      s += __shfl_xor(s, 16);
      s += __shfl_xor(s, 32);
      if (lg == 0) headbuf[t & 1][l16][w] = s;
    }

    lgkm_barrier();

    if (DO_HEAD) {
      if (tid < 16) {
        const float* hbp = headbuf[t & 1][tid];
        float s = hbp[0] + hbp[1] + hbp[2] + hbp[3] + hbp[4] + hbp[5] + hbp[6] + hbp[7];
        out[(size_t)(b0 + tid) * 91 + (tcol0 + t)] = s + hb;
      }
    }
  }

#pragma unroll
  for (int nt = 0; nt < 2; ++nt) {
    float4 c4 = {c_reg[nt][0], c_reg[nt][1], c_reg[nt][2], c_reg[nt][3]};
    *(float4*)&c_state[(size_t)(b0 + l16) * 256 + (w * 2 + nt) * 16 + lg * 4] = c4;
  }
  for (int idx = tid; idx < 16 * 256; idx += 512)
    h_state[(size_t)(b0 + (idx >> 8)) * 256 + (idx & 255)] = h_lds[ct & 1][idx >> 8][idx & 255];
}

// ---------------------------------------------------------------------------
// R10 split rec (verbatim): 32 blocks x 512 thr, deferred exchange.
// ---------------------------------------------------------------------------
template <int DO_HEAD>
__global__ __launch_bounds__(512, 2) void rec_split(
    const uint32_t* __restrict__ xp, const float* __restrict__ Whh,
    float* __restrict__ c_state, uint16_t* __restrict__ h_state,
    float* __restrict__ out, const float* __restrict__ headW,
    const float* __restrict__ headb, uint32_t* __restrict__ flags,
    unsigned long long* __restrict__ hx, uint32_t* __restrict__ hxh,
    int ct, int t0, int phase) {
  __shared__ short8 B_lds[64 * 64];
  __shared__ uint16_t h_lds[2][16][264];
  __shared__ float headbuf[16][8];

  const int tid = threadIdx.x, w = tid >> 6, l = tid & 63;
  const int l16 = l & 15, lg = l >> 4;
  const int blk = blockIdx.x;
  const int pair = blk & 15, s = blk >> 4, sp = 1 - s;
  const int b0 = pair * 16;
  const int ctile = s * 8 + w;
  uint32_t* const pflag = flags + (phase * 16 + pair) * 2 + sp;
  uint32_t* const myflag = flags + (phase * 16 + pair) * 2 + s;

  short8 bv[24];
#pragma unroll
  for (int g = 0; g < 4; ++g) {
    const float wsc = (g == 2) ? (2.f * L2E) : -L2E;
#pragma unroll
    for (int kk = 0; kk < 8; ++kk) {
      const int kt = (kk < 4) ? (4 * s + kk) : (4 * sp + (kk - 4));
      const int row = (g * 16 + ctile) * 16 + l16;
      const float* sw = Whh + (size_t)row * 256 + kt * 32 + lg * 8;
      short8 fr;
#pragma unroll
      for (int e = 0; e < 8; ++e) fr[e] = (short)f2bf(sw[e] * wsc);
      if (kk <= 5) bv[g * 6 + kk] = fr;
      else B_lds[(w * 8 + g * 2 + (kk - 6)) * 64 + l] = fr;
    }
  }

  float c_reg[4];
  {
    float4 c4 = *(const float4*)&c_state[(size_t)(b0 + l16) * 256 +
                                         ctile * 16 + lg * 4];
    c_reg[0] = c4.x; c_reg[1] = c4.y; c_reg[2] = c4.z; c_reg[3] = c4.w;
  }
  for (int idx = tid; idx < 16 * 256; idx += 512)
    h_lds[0][idx >> 8][idx & 255] = h_state[(size_t)(b0 + (idx >> 8)) * 256 + (idx & 255)];
  float4 hw4 = *(const float4*)&headW[ctile * 16 + lg * 4];
  const float hb = headb[0];

  const uint32_t* xpb = xp + ((size_t)(pair * 64 + ctile) * 64 + l) * 2;
  u32x2 xpf[4];
#pragma unroll
  for (int g = 0; g < 4; ++g)
    xpf[g] = *(const u32x2*)(xpb + (size_t)g * 2048);

  __syncthreads();

  u32x2 h_last;
  h_last[0] = 0; h_last[1] = 0;
  float hsum_prev = 0.f;

  for (int t = 0; t < ct; ++t) {
    const int cur = t & 1, nxt = cur ^ 1;
    const int tn = (t + 1 < ct) ? t + 1 : t;
    const int par = t & 1;

    unsigned long long pv = 0ull;
    if (t > 0) {
      const uint32_t tgt = (uint32_t)(t0 + t);
      __builtin_amdgcn_sched_barrier(0);
      uint32_t f;
      do {
        f = __hip_atomic_load(pflag, __ATOMIC_RELAXED, __HIP_MEMORY_SCOPE_AGENT);
      } while ((int)(f - tgt) < 0);
      __builtin_amdgcn_sched_barrier(0);
      pv = __hip_atomic_load(
          hx + ((size_t)((pair * 2 + sp) * 2 + ((t - 1) & 1)) * 512) +
              (w * 4 + lg) * 16 + l16,
          __ATOMIC_RELAXED, __HIP_MEMORY_SCOPE_AGENT);
      if (DO_HEAD && s == 0 && tid < 16) {
        uint32_t pp = __hip_atomic_load(
            hxh + ((pair * 2 + sp) * 2 + ((t - 1) & 1)) * 16 + tid,
            __ATOMIC_RELAXED, __HIP_MEMORY_SCOPE_AGENT);
        out[(size_t)(b0 + tid) * 91 + (t0 + t - 1)] =
            hsum_prev + __uint_as_float(pp) + hb;
      }
    }

    f32x4 acc[4];
#pragma unroll
    for (int g = 0; g < 4; ++g) {
      f32x4 ai;
      ai[0] = bfhalf(xpf[g][0], 0);
      ai[1] = bfhalf(xpf[g][0], 1);
      ai[2] = bfhalf(xpf[g][1], 0);
      ai[3] = bfhalf(xpf[g][1], 1);
      acc[g] = ai;
    }
#pragma unroll
    for (int kk = 0; kk < 4; ++kk) {
      short8 hf = *(const short8*)(&h_lds[cur][l16][(4 * s + kk) * 32 + lg * 8]);
#pragma unroll
      for (int g = 0; g < 4; ++g)
        acc[g] = MFMA(bv[g * 6 + kk], hf, acc[g]);
    }

    if (t > 0) {
      u32x2 pw;
      pw[0] = (uint32_t)pv;
      pw[1] = (uint32_t)(pv >> 32);
      *(u32x2*)(&h_lds[cur][l16][sp * 128 + w * 16 + lg * 4]) = pw;
      lgkm_barrier();
    }

#pragma unroll
    for (int kk = 0; kk < 4; ++kk) {
      short8 hf = *(const short8*)(&h_lds[cur][l16][(4 * sp + kk) * 32 + lg * 8]);
#pragma unroll
      for (int g = 0; g < 4; ++g) {
        if (kk < 2) acc[g] = MFMA(bv[g * 6 + 4 + kk], hf, acc[g]);
        else acc[g] = MFMA(B_lds[(w * 8 + g * 2 + (kk - 2)) * 64 + l], hf, acc[g]);
      }
    }

    float hv[4];
#pragma unroll
    for (int j = 0; j < 4; ++j) {
      float ei = ex2(acc[0][j]);
      float ef = ex2(acc[1][j]);
      float eg = ex2(acc[2][j]);
      float eo = ex2(acc[3][j]);
      float eip = 1.f + ei, egp = eg + 1.f, efp = 1.f + ef;
      float d1 = eip * egp;
      float R = rcp(d1 * efp);
      float sitg = (eg - 1.f) * efp * R;
      float cc = fmaf(c_reg[j] * d1, R, sitg);
      c_reg[j] = cc;
      float ec = ex2(cc * (2.f * L2E));
      float hh = (ec - 1.f) * rcp((1.f + eo) * (ec + 1.f));
      hv[j] = hh;
    }

    h_last[0] = cvtpk(hv[0], hv[1]);
    h_last[1] = cvtpk(hv[2], hv[3]);
    *(u32x2*)(&h_lds[nxt][l16][ctile * 16 + lg * 4]) = h_last;
    {
      unsigned long long v64 =
          ((unsigned long long)h_last[1] << 32) | (unsigned long long)h_last[0];
      __hip_atomic_store(
          hx + ((size_t)((pair * 2 + s) * 2 + par) * 512) + (w * 4 + lg) * 16 + l16,
          v64, __ATOMIC_RELAXED, __HIP_MEMORY_SCOPE_AGENT);
    }

#pragma unroll
    for (int g = 0; g < 4; ++g)
      xpf[g] = *(const u32x2*)(xpb + (size_t)tn * 131072 + g * 2048);

    if (DO_HEAD) {
      float hp = fmaf(hv[0], hw4.x, fmaf(hv[1], hw4.y,
                 fmaf(hv[2], hw4.z, hv[3] * hw4.w)));
      hp += __shfl_xor(hp, 16);
      hp += __shfl_xor(hp, 32);
      if (lg == 0) headbuf[l16][w] = hp;
    }

    vm_drain4();
    lgkm_barrier();

    if (DO_HEAD) {
      if (tid < 16) {
        const float* hbp = headbuf[tid];
        hsum_prev = hbp[0] + hbp[1] + hbp[2] + hbp[3] +
                    hbp[4] + hbp[5] + hbp[6] + hbp[7];
        __hip_atomic_store(hxh + ((pair * 2 + s) * 2 + par) * 16 + tid,
                           __float_as_uint(hsum_prev), __ATOMIC_RELAXED,
                           __HIP_MEMORY_SCOPE_AGENT);
      }
      vm_drain4();
    }
    if (tid == 0)
      __hip_atomic_store(myflag, (uint32_t)(t0 + t + 1), __ATOMIC_RELAXED,
                         __HIP_MEMORY_SCOPE_AGENT);
  }

  {
    float4 c4 = {c_reg[0], c_reg[1], c_reg[2], c_reg[3]};
    *(float4*)&c_state[(size_t)(b0 + l16) * 256 + ctile * 16 + lg * 4] = c4;
  }

  if (s == 0) {
    const uint32_t tgt = (uint32_t)(t0 + ct);
    __builtin_amdgcn_sched_barrier(0);
    uint32_t f;
    do {
      f = __hip_atomic_load(pflag, __ATOMIC_RELAXED, __HIP_MEMORY_SCOPE_AGENT);
    } while ((int)(f - tgt) < 0);
    __builtin_amdgcn_sched_barrier(0);
    unsigned long long pv = __hip_atomic_load(
        hx + ((size_t)((pair * 2 + sp) * 2 + ((ct - 1) & 1)) * 512) +
            (w * 4 + lg) * 16 + l16,
        __ATOMIC_RELAXED, __HIP_MEMORY_SCOPE_AGENT);
    u32x2 pw;
    pw[0] = (uint32_t)pv;
    pw[1] = (uint32_t)(pv >> 32);
    *(u32x2*)&h_state[(size_t)(b0 + l16) * 256 + 128 + w * 16 + lg * 4] = pw;
    *(u32x2*)&h_state[(size_t)(b0 + l16) * 256 + w * 16 + lg * 4] = h_last;
    if (DO_HEAD && tid < 16) {
      uint32_t pp = __hip_atomic_load(
          hxh + ((pair * 2 + sp) * 2 + ((ct - 1) & 1)) * 16 + tid,
          __ATOMIC_RELAXED, __HIP_MEMORY_SCOPE_AGENT);
      out[(size_t)(b0 + tid) * 91 + (t0 + ct - 1)] =
          hsum_prev + __uint_as_float(pp) + hb;
    }
  }
}

// ---------------------------------------------------------------------------
extern "C" void kernel_launch(void* const* d_in, const int* in_sizes, int n_in,
                              void* d_out, int out_size, void* d_ws, size_t ws_size,
                              hipStream_t stream) {
  const float* headW = (const float*)d_in[12];
  const float* headb = (const float*)d_in[13];
  float* out = (float*)d_out;
  char* ws = (char*)d_ws;

  const int T0 = in_sizes[0] / (256 * 64);
  const int T1 = in_sizes[1] / (256 * 32);
  const int T2 = in_sizes[2] / (256 * 16);
  const size_t s0 = (size_t)T0 << 19, s1 = (size_t)T1 << 19, s2 = (size_t)T2 << 19;
  const size_t hdr = 667648;  // state 384KB + flags 4KB + hx 256KB + hxh 8KB

  if (ws_size >= hdr + s0 + s1 + s2) {
    float* c_state = (float*)ws;                           // 256 KB
    uint16_t* h_state = (uint16_t*)(ws + 262144);          // 128 KB
    uint32_t* flags = (uint32_t*)(ws + 393216);            // 4 KB slot
    unsigned long long* hx = (unsigned long long*)(ws + 397312);  // 256 KB
    uint32_t* hxh = (uint32_t*)(ws + 659456);              // 8 KB slot
    uint32_t* xp0 = (uint32_t*)(ws + hdr);
    uint32_t* xp1 = (uint32_t*)(ws + hdr + s0);
    uint32_t* xp2 = (uint32_t*)(ws + hdr + s0 + s1);

    init_kernel<<<256, 256, 0, stream>>>(c_state, h_state, out, flags);
    // all projections first -> rec dispatches run back-to-back
    xproj_kernel<64><<<dim3(T0 * 2), 512, 0, stream>>>(
        (const float*)d_in[0], (const float*)d_in[3], (const float*)d_in[5], xp0, 0, T0);
    xproj_kernel<32><<<dim3(T1 * 2), 512, 0, stream>>>(
        (const float*)d_in[1], (const float*)d_in[6], (const float*)d_in[8], xp1, 0, T1);
    xproj_kernel<16><<<dim3(T2 * 2), 512, 0, stream>>>(
        (const float*)d_in[2], (const float*)d_in[9], (const float*)d_in[11], xp2, 0, T2);
    // encoder: R8 16-block kernel (best per-step at T=365)
    rec_kernel<0><<<16, 512, 0, stream>>>(xp0, (const float*)d_in[4], c_state,
                                          h_state, out, headW, headb, T0, 0);
    // decoders: R10 32-block split kernel (best per-step amortized at small T)
    rec_split<0><<<32, 512, 0, stream>>>(xp1, (const float*)d_in[7], c_state,
                                         h_state, out, headW, headb, flags, hx,
                                         hxh, T1, 0, 1);
    rec_split<1><<<32, 512, 0, stream>>>(xp2, (const float*)d_in[10], c_state,
                                         h_state, out, headW, headb, flags, hx,
                                         hxh, T2, 0, 2);
    return;
  }

  // ---- fallback: verbatim round-8 chunked path ----
  float* c_state = (float*)ws;                      // 256 KB
  uint16_t* h_state = (uint16_t*)(ws + 262144);     // 128 KB
  uint32_t* xp = (uint32_t*)(ws + 393216);          // chunk buffer, 512 KB per t

  int ct_max = 1;
  if (ws_size > 393216 + 512 * 1024) {
    size_t c = (ws_size - 393216) / (512 * 1024);
    ct_max = (c > 365) ? 365 : (int)c;
  }

  init_kernel<<<256, 256, 0, stream>>>(c_state, h_state, out, nullptr);

  struct Phase { const float* x; const float* Wih; const float* Whh; const float* b; int T; int D; int head; };
  Phase ph[3] = {
      {(const float*)d_in[0], (const float*)d_in[3], (const float*)d_in[4], (const float*)d_in[5], T0, 64, 0},
      {(const float*)d_in[1], (const float*)d_in[6], (const float*)d_in[7], (const float*)d_in[8], T1, 32, 0},
      {(const float*)d_in[2], (const float*)d_in[9], (const float*)d_in[10], (const float*)d_in[11], T2, 16, 1},
  };

  for (int pi = 0; pi < 3; ++pi) {
    const Phase& P = ph[pi];
    for (int t0 = 0; t0 < P.T; t0 += ct_max) {
      int ct = (P.T - t0 < ct_max) ? (P.T - t0) : ct_max;
      dim3 g(ct * 2);
      if (P.D == 64)
        xproj_kernel<64><<<g, 512, 0, stream>>>(P.x, P.Wih, P.b, xp, t0, P.T);
      else if (P.D == 32)
        xproj_kernel<32><<<g, 512, 0, stream>>>(P.x, P.Wih, P.b, xp, t0, P.T);
      else
        xproj_kernel<16><<<g, 512, 0, stream>>>(P.x, P.Wih, P.b, xp, t0, P.T);
      if (P.head)
        rec_kernel<1><<<16, 512, 0, stream>>>(xp, P.Whh, c_state, h_state, out,
                                              headW, headb, ct, t0);
      else
        rec_kernel<0><<<16, 512, 0, stream>>>(xp, P.Whh, c_state, h_state, out,
                                              headW, headb, ct, t0);
    }
  }
}

// Round 15
// 1205.919 us; speedup vs baseline: 1.3909x; 1.0304x over previous
//
#include <hip/hip_runtime.h>
#include <stdint.h>

// ============================================================================
// S2S2S LSTM forecaster, MI355X.  Round 15 = round-14 assembly with dispatch
// fusion at the boundaries only (rec t-loops byte-identical):
//   - xproj_mega: ONE dispatch = all 3 phase projections (proven body as a
//     device function) + misc block zeroing out[76..90] and split-flags.
//   - enc rec: ZINIT=1 (zero c/h in prologue, skip state load) -- t-loop
//     untouched; writeback kept for the decoders.
//   - decoders: R10 32-block split rec, verbatim.
//   6 dispatches -> 4.  Fallback: R8 chunked path (proven) if ws too small.
// Output: cols 0..75 = future-decoder head, 76..90 = 0 (ref overwrites out_f).
// ============================================================================

typedef __attribute__((ext_vector_type(8))) short short8;  // 8 x bf16
typedef __attribute__((ext_vector_type(4))) float f32x4;   // MFMA acc
typedef __attribute__((ext_vector_type(2))) unsigned int u32x2;
typedef __attribute__((ext_vector_type(4))) unsigned int u32x4;

#define L2E 1.4426950408889634f

__device__ __forceinline__ uint16_t f2bf(float f) {  // fp32 -> bf16 bits, RNE
  uint32_t x = __float_as_uint(f);
  x += 0x7fffu + ((x >> 16) & 1u);
  return (uint16_t)(x >> 16);
}
__device__ __forceinline__ uint32_t cvtpk(float lo, float hi) {  // 1-inst pack
  uint32_t r;
  asm("v_cvt_pk_bf16_f32 %0, %1, %2" : "=v"(r) : "v"(lo), "v"(hi));
  return r;
}
__device__ __forceinline__ float bfhalf(uint32_t w, int hi) {  // bf16 -> fp32
  return __uint_as_float(hi ? (w & 0xffff0000u) : (w << 16));
}
__device__ __forceinline__ f32x4 MFMA(short8 a, short8 b, f32x4 c) {
  return __builtin_amdgcn_mfma_f32_16x16x32_bf16(a, b, c, 0, 0, 0);
}
__device__ __forceinline__ float ex2(float x) { return __builtin_amdgcn_exp2f(x); }
__device__ __forceinline__ float rcp(float x) { return __builtin_amdgcn_rcpf(x); }

// pack 8 consecutive floats (16B-aligned) * scale -> short8 of bf16
__device__ __forceinline__ short8 pack8s(const float* s, float sc) {
  float4 q0 = *(const float4*)s, q1 = *(const float4*)(s + 4);
  u32x4 t;
  t[0] = cvtpk(q0.x * sc, q0.y * sc);
  t[1] = cvtpk(q0.z * sc, q0.w * sc);
  t[2] = cvtpk(q1.x * sc, q1.y * sc);
  t[3] = cvtpk(q1.z * sc, q1.w * sc);
  return *(short8*)&t;
}

// Barrier waiting only LDS ops (lgkmcnt), NOT vmcnt.
__device__ __forceinline__ void lgkm_barrier() {
  __builtin_amdgcn_sched_barrier(0);
  asm volatile("s_waitcnt lgkmcnt(0)" ::: "memory");
  __builtin_amdgcn_s_barrier();
  __builtin_amdgcn_sched_barrier(0);
}
// drain oldest vmem ops but keep 4 xp prefetch loads in flight
__device__ __forceinline__ void vm_drain4() {
  __builtin_amdgcn_sched_barrier(0);
  asm volatile("s_waitcnt vmcnt(4)" ::: "memory");
  __builtin_amdgcn_sched_barrier(0);
}

// ---------------------------------------------------------------------------
__global__ void init_kernel(float* c_state, uint16_t* h_state, float* out) {
  int i = blockIdx.x * 256 + threadIdx.x;
  if (i < 65536) { c_state[i] = 0.f; h_state[i] = 0; }
  if (i < 256 * 91) out[i] = 0.f;
}

// ---------------------------------------------------------------------------
// xproj body (proven): transposed, pre-scaled C^T fragments,
// xp[tc][btile][rowtile][lane][2], value = (x@Wih^T+b)*(g? +2log2e : -log2e).
// ---------------------------------------------------------------------------
template <int DIN>
__device__ __forceinline__ void xproj_body(
    const float* __restrict__ x, const float* __restrict__ Wih,
    const float* __restrict__ bias, uint32_t* __restrict__ xp,
    int T, int blk, int tid) {
  const int w = tid >> 6, l = tid & 63;
  const int l16 = l & 15, lg = l >> 4;
  const int tc = blk >> 1;
  const int sub = blk & 1;
  const int t = tc;
  constexpr int KT = (DIN + 31) / 32;

  short8 bfr[8][KT];
  float4 bias4[8];
#pragma unroll
  for (int ni = 0; ni < 8; ++ni) {
    const int n = (w * 8 + ni) * 16 + l16;
    bias4[ni] = *(const float4*)&bias[(w * 8 + ni) * 16 + lg * 4];
#pragma unroll
    for (int kt = 0; kt < KT; ++kt) {
      const int k0 = kt * 32 + lg * 8;
      short8 fr;
#pragma unroll
      for (int e = 0; e < 8; ++e) fr[e] = 0;
      if (k0 + 8 <= DIN) fr = pack8s(Wih + (size_t)n * DIN + k0, 1.f);
      bfr[ni][kt] = fr;
    }
  }

  for (int mi = 0; mi < 8; ++mi) {
    const int btile = sub * 8 + mi;
    const int b = btile * 16 + l16;
    short8 af[KT];
#pragma unroll
    for (int kt = 0; kt < KT; ++kt) {
      const int k0 = kt * 32 + lg * 8;
      short8 fr;
#pragma unroll
      for (int e = 0; e < 8; ++e) fr[e] = 0;
      if (k0 + 8 <= DIN) fr = pack8s(x + ((size_t)b * T + t) * DIN + k0, 1.f);
      af[kt] = fr;
    }
#pragma unroll
    for (int ni = 0; ni < 8; ++ni) {
      f32x4 acc = {0.f, 0.f, 0.f, 0.f};
#pragma unroll
      for (int kt = 0; kt < KT; ++kt) acc = MFMA(bfr[ni][kt], af[kt], acc);
      const int nt = w * 8 + ni;
      const float sc = ((nt >> 4) == 2) ? (2.f * L2E) : -L2E;
      size_t idx = ((((size_t)tc * 16 + btile) * 64 + nt) * 64 + l) * 2;
      u32x2 v;
      v[0] = cvtpk((acc[0] + bias4[ni].x) * sc, (acc[1] + bias4[ni].y) * sc);
      v[1] = cvtpk((acc[2] + bias4[ni].z) * sc, (acc[3] + bias4[ni].w) * sc);
      *(u32x2*)(xp + idx) = v;
    }
  }
}

// standalone (fallback path, chunked)
template <int DIN>
__global__ __launch_bounds__(512) void xproj_kernel(
    const float* __restrict__ x, const float* __restrict__ Wih,
    const float* __restrict__ bias, uint32_t* __restrict__ xp,
    int t0, int T) {
  const int tid = threadIdx.x;
  const int blk = blockIdx.x + t0 * 2;  // body uses tc=blk>>1 as absolute t
  xproj_body<DIN>(x, Wih, bias, xp - (size_t)t0 * 131072, T, blk, tid);
}

// ---------------------------------------------------------------------------
// xproj_mega: one dispatch = all 3 projections + misc zeroing.
// blocks [0,n0) phase0, [n0,n0+n1) phase1, [n0+n1,n0+n1+n2) phase2,
// block n0+n1+n2: zero out[:,76..91) and flags[0..96).
// ---------------------------------------------------------------------------
__global__ __launch_bounds__(512) void xproj_mega(
    const float* __restrict__ x0, const float* __restrict__ Wih0,
    const float* __restrict__ b0, uint32_t* __restrict__ xp0,
    const float* __restrict__ x1, const float* __restrict__ Wih1,
    const float* __restrict__ b1, uint32_t* __restrict__ xp1,
    const float* __restrict__ x2, const float* __restrict__ Wih2,
    const float* __restrict__ b2, uint32_t* __restrict__ xp2,
    float* __restrict__ out, uint32_t* __restrict__ flags,
    int T0, int T1, int T2) {
  const int tid = threadIdx.x;
  const int n0 = T0 * 2, n1 = T1 * 2, n2 = T2 * 2;
  const int b = blockIdx.x;
  if (b < n0) {
    xproj_body<64>(x0, Wih0, b0, xp0, T0, b, tid);
  } else if (b < n0 + n1) {
    xproj_body<32>(x1, Wih1, b1, xp1, T1, b - n0, tid);
  } else if (b < n0 + n1 + n2) {
    xproj_body<16>(x2, Wih2, b2, xp2, T2, b - n0 - n1, tid);
  } else {
    // misc: zero out cols 76..90 (3840 floats) + flags (96 u32)
    for (int i = tid; i < 256 * 15; i += 512)
      out[(size_t)(i / 15) * 91 + 76 + (i % 15)] = 0.f;
    if (tid < 96) flags[tid] = 0;
  }
}

// ---------------------------------------------------------------------------
// R8 rec_kernel: 16 blocks x 512 thr. ZINIT=1: zero-state prologue (enc).
// t-loop byte-identical to round 8.
// ---------------------------------------------------------------------------
template <int DO_HEAD, int ZINIT>
__global__ __launch_bounds__(512, 2) void rec_kernel(
    const uint32_t* __restrict__ xp, const float* __restrict__ Whh,
    float* __restrict__ c_state, uint16_t* __restrict__ h_state,
    float* __restrict__ out, const float* __restrict__ headW,
    const float* __restrict__ headb, int ct, int tcol0) {
  __shared__ short8 B_lds[8 * 16 * 64];
  __shared__ uint16_t h_lds[2][16][264];
  __shared__ float headbuf[2][16][8];

  const int tid = threadIdx.x, w = tid >> 6, l = tid & 63;
  const int l16 = l & 15, lg = l >> 4;
  const int blk = blockIdx.x, b0 = blk * 16;

  short8 bv[48];
#pragma unroll
  for (int g = 0; g < 4; ++g) {
    const float wsc = (g == 2) ? (2.f * L2E) : -L2E;
#pragma unroll
    for (int nt = 0; nt < 2; ++nt)
#pragma unroll
      for (int kt = 0; kt < 8; ++kt) {
        const int row = (g * 16 + w * 2 + nt) * 16 + l16;
        const float* s = Whh + (size_t)row * 256 + kt * 32 + lg * 8;
        short8 fr;
#pragma unroll
        for (int e = 0; e < 8; ++e) fr[e] = (short)f2bf(s[e] * wsc);
        const int tile = g * 2 + nt;
        if (kt <= 5) bv[tile * 6 + kt] = fr;
        else B_lds[(w * 16 + (kt - 6) * 8 + tile) * 64 + l] = fr;
      }
  }

  float c_reg[2][4];
  if (ZINIT) {
#pragma unroll
    for (int nt = 0; nt < 2; ++nt)
#pragma unroll
      for (int j = 0; j < 4; ++j) c_reg[nt][j] = 0.f;
    for (int idx = tid; idx < 16 * 264; idx += 512)
      ((uint16_t*)h_lds)[idx] = 0;   // h_lds[0] flat
  } else {
#pragma unroll
    for (int nt = 0; nt < 2; ++nt) {
      float4 c4 = *(const float4*)&c_state[(size_t)(b0 + l16) * 256 +
                                           (w * 2 + nt) * 16 + lg * 4];
      c_reg[nt][0] = c4.x; c_reg[nt][1] = c4.y;
      c_reg[nt][2] = c4.z; c_reg[nt][3] = c4.w;
    }
    for (int idx = tid; idx < 16 * 256; idx += 512)
      h_lds[0][idx >> 8][idx & 255] = h_state[(size_t)(b0 + (idx >> 8)) * 256 + (idx & 255)];
  }
  float4 hw4[2];
#pragma unroll
  for (int nt = 0; nt < 2; ++nt)
    hw4[nt] = *(const float4*)&headW[(w * 2 + nt) * 16 + lg * 4];
  const float hb = headb[0];

  const uint32_t* xpb = xp + ((size_t)(blk * 64 + w * 2) * 64 + l) * 2;
  u32x2 xpf[2][4];
#pragma unroll
  for (int nt = 0; nt < 2; ++nt)
#pragma unroll
    for (int g = 0; g < 4; ++g)
      xpf[nt][g] = *(const u32x2*)(xpb + (size_t)g * 2048 + nt * 128);

  __syncthreads();

  for (int t = 0; t < ct; ++t) {
    const int cur = t & 1, nxt = cur ^ 1;
    const int tn = (t + 1 < ct) ? t + 1 : t;
    float hp = 0.f;

#pragma unroll
    for (int nt = 0; nt < 2; ++nt) {
      f32x4 acc[4];
#pragma unroll
      for (int g = 0; g < 4; ++g) {
        f32x4 ai;
        ai[0] = bfhalf(xpf[nt][g][0], 0);
        ai[1] = bfhalf(xpf[nt][g][0], 1);
        ai[2] = bfhalf(xpf[nt][g][1], 0);
        ai[3] = bfhalf(xpf[nt][g][1], 1);
        acc[g] = ai;
      }
#pragma unroll
      for (int kt = 0; kt <= 5; ++kt) {
        short8 hf = *(const short8*)(&h_lds[cur][l16][kt * 32 + lg * 8]);
#pragma unroll
        for (int g = 0; g < 4; ++g)
          acc[g] = MFMA(bv[(g * 2 + nt) * 6 + kt], hf, acc[g]);
      }
#pragma unroll
      for (int kt = 6; kt <= 7; ++kt) {
        short8 hf = *(const short8*)(&h_lds[cur][l16][kt * 32 + lg * 8]);
#pragma unroll
        for (int g = 0; g < 4; ++g)
          acc[g] = MFMA(B_lds[(w * 16 + (kt - 6) * 8 + g * 2 + nt) * 64 + l], hf, acc[g]);
      }

      float hv[4];
#pragma unroll
      for (int j = 0; j < 4; ++j) {
        float ei = ex2(acc[0][j]);
        float ef = ex2(acc[1][j]);
        float eg = ex2(acc[2][j]);
        float eo = ex2(acc[3][j]);
        float eip = 1.f + ei, egp = eg + 1.f, efp = 1.f + ef;
        float d1 = eip * egp;
        float R = rcp(d1 * efp);
        float sitg = (eg - 1.f) * efp * R;
        float cc = fmaf(c_reg[nt][j] * d1, R, sitg);
        c_reg[nt][j] = cc;
        float ec = ex2(cc * (2.f * L2E));
        float hh = (ec - 1.f) * rcp((1.f + eo) * (ec + 1.f));
        hv[j] = hh;
      }
      if (DO_HEAD) {
        hp = fmaf(hv[0], hw4[nt].x, hp); hp = fmaf(hv[1], hw4[nt].y, hp);
        hp = fmaf(hv[2], hw4[nt].z, hp); hp = fmaf(hv[3], hw4[nt].w, hp);
      }
      {
        u32x2 hwrd;
        hwrd[0] = cvtpk(hv[0], hv[1]);
        hwrd[1] = cvtpk(hv[2], hv[3]);
        *(u32x2*)(&h_lds[nxt][l16][(w * 2 + nt) * 16 + lg * 4]) = hwrd;
      }
#pragma unroll
      for (int g = 0; g < 4; ++g)
        xpf[nt][g] = *(const u32x2*)(xpb + (size_t)tn * 131072 + g * 2048 + nt * 128);
    }

    if (DO_HEAD) {
      float s = hp;
      s += __shfl_xor(s, 16);
      s += __shfl_xor(s, 32);
      if (lg == 0) headbuf[t & 1][l16][w] = s;
    }

    lgkm_barrier();

    if (DO_HEAD) {
      if (tid < 16) {
        const float* hbp = headbuf[t & 1][tid];
        float s = hbp[0] + hbp[1] + hbp[2] + hbp[3] + hbp[4] + hbp[5] + hbp[6] + hbp[7];
        out[(size_t)(b0 + tid) * 91 + (tcol0 + t)] = s + hb;
      }
    }
  }

#pragma unroll
  for (int nt = 0; nt < 2; ++nt) {
    float4 c4 = {c_reg[nt][0], c_reg[nt][1], c_reg[nt][2], c_reg[nt][3]};
    *(float4*)&c_state[(size_t)(b0 + l16) * 256 + (w * 2 + nt) * 16 + lg * 4] = c4;
  }
  for (int idx = tid; idx < 16 * 256; idx += 512)
    h_state[(size_t)(b0 + (idx >> 8)) * 256 + (idx & 255)] = h_lds[ct & 1][idx >> 8][idx & 255];
}

// ---------------------------------------------------------------------------
// R10 split rec (verbatim): 32 blocks x 512 thr, deferred exchange.
// ---------------------------------------------------------------------------
template <int DO_HEAD>
__global__ __launch_bounds__(512, 2) void rec_split(
    const uint32_t* __restrict__ xp, const float* __restrict__ Whh,
    float* __restrict__ c_state, uint16_t* __restrict__ h_state,
    float* __restrict__ out, const float* __restrict__ headW,
    const float* __restrict__ headb, uint32_t* __restrict__ flags,
    unsigned long long* __restrict__ hx, uint32_t* __restrict__ hxh,
    int ct, int t0, int phase) {
  __shared__ short8 B_lds[64 * 64];
  __shared__ uint16_t h_lds[2][16][264];
  __shared__ float headbuf[16][8];

  const int tid = threadIdx.x, w = tid >> 6, l = tid & 63;
  const int l16 = l & 15, lg = l >> 4;
  const int blk = blockIdx.x;
  const int pair = blk & 15, s = blk >> 4, sp = 1 - s;
  const int b0 = pair * 16;
  const int ctile = s * 8 + w;
  uint32_t* const pflag = flags + (phase * 16 + pair) * 2 + sp;
  uint32_t* const myflag = flags + (phase * 16 + pair) * 2 + s;

  short8 bv[24];
#pragma unroll
  for (int g = 0; g < 4; ++g) {
    const float wsc = (g == 2) ? (2.f * L2E) : -L2E;
#pragma unroll
    for (int kk = 0; kk < 8; ++kk) {
      const int kt = (kk < 4) ? (4 * s + kk) : (4 * sp + (kk - 4));
      const int row = (g * 16 + ctile) * 16 + l16;
      const float* sw = Whh + (size_t)row * 256 + kt * 32 + lg * 8;
      short8 fr;
#pragma unroll
      for (int e = 0; e < 8; ++e) fr[e] = (short)f2bf(sw[e] * wsc);
      if (kk <= 5) bv[g * 6 + kk] = fr;
      else B_lds[(w * 8 + g * 2 + (kk - 6)) * 64 + l] = fr;
    }
  }

  float c_reg[4];
  {
    float4 c4 = *(const float4*)&c_state[(size_t)(b0 + l16) * 256 +
                                         ctile * 16 + lg * 4];
    c_reg[0] = c4.x; c_reg[1] = c4.y; c_reg[2] = c4.z; c_reg[3] = c4.w;
  }
  for (int idx = tid; idx < 16 * 256; idx += 512)
    h_lds[0][idx >> 8][idx & 255] = h_state[(size_t)(b0 + (idx >> 8)) * 256 + (idx & 255)];
  float4 hw4 = *(const float4*)&headW[ctile * 16 + lg * 4];
  const float hb = headb[0];

  const uint32_t* xpb = xp + ((size_t)(pair * 64 + ctile) * 64 + l) * 2;
  u32x2 xpf[4];
#pragma unroll
  for (int g = 0; g < 4; ++g)
    xpf[g] = *(const u32x2*)(xpb + (size_t)g * 2048);

  __syncthreads();

  u32x2 h_last;
  h_last[0] = 0; h_last[1] = 0;
  float hsum_prev = 0.f;

  for (int t = 0; t < ct; ++t) {
    const int cur = t & 1, nxt = cur ^ 1;
    const int tn = (t + 1 < ct) ? t + 1 : t;
    const int par = t & 1;

    unsigned long long pv = 0ull;
    if (t > 0) {
      const uint32_t tgt = (uint32_t)(t0 + t);
      __builtin_amdgcn_sched_barrier(0);
      uint32_t f;
      do {
        f = __hip_atomic_load(pflag, __ATOMIC_RELAXED, __HIP_MEMORY_SCOPE_AGENT);
      } while ((int)(f - tgt) < 0);
      __builtin_amdgcn_sched_barrier(0);
      pv = __hip_atomic_load(
          hx + ((size_t)((pair * 2 + sp) * 2 + ((t - 1) & 1)) * 512) +
              (w * 4 + lg) * 16 + l16,
          __ATOMIC_RELAXED, __HIP_MEMORY_SCOPE_AGENT);
      if (DO_HEAD && s == 0 && tid < 16) {
        uint32_t pp = __hip_atomic_load(
            hxh + ((pair * 2 + sp) * 2 + ((t - 1) & 1)) * 16 + tid,
            __ATOMIC_RELAXED, __HIP_MEMORY_SCOPE_AGENT);
        out[(size_t)(b0 + tid) * 91 + (t0 + t - 1)] =
            hsum_prev + __uint_as_float(pp) + hb;
      }
    }

    f32x4 acc[4];
#pragma unroll
    for (int g = 0; g < 4; ++g) {
      f32x4 ai;
      ai[0] = bfhalf(xpf[g][0], 0);
      ai[1] = bfhalf(xpf[g][0], 1);
      ai[2] = bfhalf(xpf[g][1], 0);
      ai[3] = bfhalf(xpf[g][1], 1);
      acc[g] = ai;
    }
#pragma unroll
    for (int kk = 0; kk < 4; ++kk) {
      short8 hf = *(const short8*)(&h_lds[cur][l16][(4 * s + kk) * 32 + lg * 8]);
#pragma unroll
      for (int g = 0; g < 4; ++g)
        acc[g] = MFMA(bv[g * 6 + kk], hf, acc[g]);
    }

    if (t > 0) {
      u32x2 pw;
      pw[0] = (uint32_t)pv;
      pw[1] = (uint32_t)(pv >> 32);
      *(u32x2*)(&h_lds[cur][l16][sp * 128 + w * 16 + lg * 4]) = pw;
      lgkm_barrier();
    }

#pragma unroll
    for (int kk = 0; kk < 4; ++kk) {
      short8 hf = *(const short8*)(&h_lds[cur][l16][(4 * sp + kk) * 32 + lg * 8]);
#pragma unroll
      for (int g = 0; g < 4; ++g) {
        if (kk < 2) acc[g] = MFMA(bv[g * 6 + 4 + kk], hf, acc[g]);
        else acc[g] = MFMA(B_lds[(w * 8 + g * 2 + (kk - 2)) * 64 + l], hf, acc[g]);
      }
    }

    float hv[4];
#pragma unroll
    for (int j = 0; j < 4; ++j) {
      float ei = ex2(acc[0][j]);
      float ef = ex2(acc[1][j]);
      float eg = ex2(acc[2][j]);
      float eo = ex2(acc[3][j]);
      float eip = 1.f + ei, egp = eg + 1.f, efp = 1.f + ef;
      float d1 = eip * egp;
      float R = rcp(d1 * efp);
      float sitg = (eg - 1.f) * efp * R;
      float cc = fmaf(c_reg[j] * d1, R, sitg);
      c_reg[j] = cc;
      float ec = ex2(cc * (2.f * L2E));
      float hh = (ec - 1.f) * rcp((1.f + eo) * (ec + 1.f));
      hv[j] = hh;
    }

    h_last[0] = cvtpk(hv[0], hv[1]);
    h_last[1] = cvtpk(hv[2], hv[3]);
    *(u32x2*)(&h_lds[nxt][l16][ctile * 16 + lg * 4]) = h_last;
    {
      unsigned long long v64 =
          ((unsigned long long)h_last[1] << 32) | (unsigned long long)h_last[0];
      __hip_atomic_store(
          hx + ((size_t)((pair * 2 + s) * 2 + par) * 512) + (w * 4 + lg) * 16 + l16,
          v64, __ATOMIC_RELAXED, __HIP_MEMORY_SCOPE_AGENT);
    }

#pragma unroll
    for (int g = 0; g < 4; ++g)
      xpf[g] = *(const u32x2*)(xpb + (size_t)tn * 131072 + g * 2048);

    if (DO_HEAD) {
      float hp = fmaf(hv[0], hw4.x, fmaf(hv[1], hw4.y,
                 fmaf(hv[2], hw4.z, hv[3] * hw4.w)));
      hp += __shfl_xor(hp, 16);
      hp += __shfl_xor(hp, 32);
      if (lg == 0) headbuf[l16][w] = hp;
    }

    vm_drain4();
    lgkm_barrier();

    if (DO_HEAD) {
      if (tid < 16) {
        const float* hbp = headbuf[tid];
        hsum_prev = hbp[0] + hbp[1] + hbp[2] + hbp[3] +
                    hbp[4] + hbp[5] + hbp[6] + hbp[7];
        __hip_atomic_store(hxh + ((pair * 2 + s) * 2 + par) * 16 + tid,
                           __float_as_uint(hsum_prev), __ATOMIC_RELAXED,
                           __HIP_MEMORY_SCOPE_AGENT);
      }
      vm_drain4();
    }
    if (tid == 0)
      __hip_atomic_store(myflag, (uint32_t)(t0 + t + 1), __ATOMIC_RELAXED,
                         __HIP_MEMORY_SCOPE_AGENT);
  }

  {
    float4 c4 = {c_reg[0], c_reg[1], c_reg[2], c_reg[3]};
    *(float4*)&c_state[(size_t)(b0 + l16) * 256 + ctile * 16 + lg * 4] = c4;
  }

  if (s == 0) {
    const uint32_t tgt = (uint32_t)(t0 + ct);
    __builtin_amdgcn_sched_barrier(0);
    uint32_t f;
    do {
      f = __hip_atomic_load(pflag, __ATOMIC_RELAXED, __HIP_MEMORY_SCOPE_AGENT);
    } while ((int)(f - tgt) < 0);
    __builtin_amdgcn_sched_barrier(0);
    unsigned long long pv = __hip_atomic_load(
        hx + ((size_t)((pair * 2 + sp) * 2 + ((ct - 1) & 1)) * 512) +
            (w * 4 + lg) * 16 + l16,
        __ATOMIC_RELAXED, __HIP_MEMORY_SCOPE_AGENT);
    u32x2 pw;
    pw[0] = (uint32_t)pv;
    pw[1] = (uint32_t)(pv >> 32);
    *(u32x2*)&h_state[(size_t)(b0 + l16) * 256 + 128 + w * 16 + lg * 4] = pw;
    *(u32x2*)&h_state[(size_t)(b0 + l16) * 256 + w * 16 + lg * 4] = h_last;
    if (DO_HEAD && tid < 16) {
      uint32_t pp = __hip_atomic_load(
          hxh + ((pair * 2 + sp) * 2 + ((ct - 1) & 1)) * 16 + tid,
          __ATOMIC_RELAXED, __HIP_MEMORY_SCOPE_AGENT);
      out[(size_t)(b0 + tid) * 91 + (t0 + ct - 1)] =
          hsum_prev + __uint_as_float(pp) + hb;
    }
  }
}

// ---------------------------------------------------------------------------
extern "C" void kernel_launch(void* const* d_in, const int* in_sizes, int n_in,
                              void* d_out, int out_size, void* d_ws, size_t ws_size,
                              hipStream_t stream) {
  const float* headW = (const float*)d_in[12];
  const float* headb = (const float*)d_in[13];
  float* out = (float*)d_out;
  char* ws = (char*)d_ws;

  const int T0 = in_sizes[0] / (256 * 64);
  const int T1 = in_sizes[1] / (256 * 32);
  const int T2 = in_sizes[2] / (256 * 16);
  const size_t s0 = (size_t)T0 << 19, s1 = (size_t)T1 << 19, s2 = (size_t)T2 << 19;
  const size_t hdr = 667648;  // state 384KB + flags 4KB + hx 256KB + hxh 8KB

  if (ws_size >= hdr + s0 + s1 + s2) {
    float* c_state = (float*)ws;                           // 256 KB
    uint16_t* h_state = (uint16_t*)(ws + 262144);          // 128 KB
    uint32_t* flags = (uint32_t*)(ws + 393216);            // 4 KB slot
    unsigned long long* hx = (unsigned long long*)(ws + 397312);  // 256 KB
    uint32_t* hxh = (uint32_t*)(ws + 659456);              // 8 KB slot
    uint32_t* xp0 = (uint32_t*)(ws + hdr);
    uint32_t* xp1 = (uint32_t*)(ws + hdr + s0);
    uint32_t* xp2 = (uint32_t*)(ws + hdr + s0 + s1);

    // 1) all projections + misc zeroing in ONE dispatch
    const int nblk = T0 * 2 + T1 * 2 + T2 * 2 + 1;
    xproj_mega<<<dim3(nblk), 512, 0, stream>>>(
        (const float*)d_in[0], (const float*)d_in[3], (const float*)d_in[5], xp0,
        (const float*)d_in[1], (const float*)d_in[6], (const float*)d_in[8], xp1,
        (const float*)d_in[2], (const float*)d_in[9], (const float*)d_in[11], xp2,
        out, flags, T0, T1, T2);
    // 2) encoder: R8 16-block kernel, zero-init prologue (no state read)
    rec_kernel<0, 1><<<16, 512, 0, stream>>>(xp0, (const float*)d_in[4], c_state,
                                             h_state, out, headW, headb, T0, 0);
    // 3,4) decoders: R10 32-block split kernel
    rec_split<0><<<32, 512, 0, stream>>>(xp1, (const float*)d_in[7], c_state,
                                         h_state, out, headW, headb, flags, hx,
                                         hxh, T1, 0, 1);
    rec_split<1><<<32, 512, 0, stream>>>(xp2, (const float*)d_in[10], c_state,
                                         h_state, out, headW, headb, flags, hx,
                                         hxh, T2, 0, 2);
    return;
  }

  // ---- fallback: verbatim round-8 chunked path ----
  float* c_state = (float*)ws;                      // 256 KB
  uint16_t* h_state = (uint16_t*)(ws + 262144);     // 128 KB
  uint32_t* xp = (uint32_t*)(ws + 393216);          // chunk buffer, 512 KB per t

  int ct_max = 1;
  if (ws_size > 393216 + 512 * 1024) {
    size_t c = (ws_size - 393216) / (512 * 1024);
    ct_max = (c > 365) ? 365 : (int)c;
  }

  init_kernel<<<256, 256, 0, stream>>>(c_state, h_state, out);

  struct Phase { const float* x; const float* Wih; const float* Whh; const float* b; int T; int D; int head; };
  Phase ph[3] = {
      {(const float*)d_in[0], (const float*)d_in[3], (const float*)d_in[4], (const float*)d_in[5], T0, 64, 0},
      {(const float*)d_in[1], (const float*)d_in[6], (const float*)d_in[7], (const float*)d_in[8], T1, 32, 0},
      {(const float*)d_in[2], (const float*)d_in[9], (const float*)d_in[10], (const float*)d_in[11], T2, 16, 1},
  };

  for (int pi = 0; pi < 3; ++pi) {
    const Phase& P = ph[pi];
    for (int t0 = 0; t0 < P.T; t0 += ct_max) {
      int ct = (P.T - t0 < ct_max) ? (P.T - t0) : ct_max;
      dim3 g(ct * 2);
      if (P.D == 64)
        xproj_kernel<64><<<g, 512, 0, stream>>>(P.x, P.Wih, P.b, xp, t0, P.T);
      else if (P.D == 32)
        xproj_kernel<32><<<g, 512, 0, stream>>>(P.x, P.Wih, P.b, xp, t0, P.T);
      else
        xproj_kernel<16><<<g, 512, 0, stream>>>(P.x, P.Wih, P.b, xp, t0, P.T);
      if (P.head)
        rec_kernel<1, 0><<<16, 512, 0, stream>>>(xp, P.Whh, c_state, h_state, out,
                                                 headW, headb, ct, t0);
      else
        rec_kernel<0, 0><<<16, 512, 0, stream>>>(xp, P.Whh, c_state, h_state, out,
                                                 headW, headb, ct, t0);
    }
  }
}

// Round 16
// 1193.294 us; speedup vs baseline: 1.4056x; 1.0106x over previous
//
#include <hip/hip_runtime.h>
#include <stdint.h>

// ============================================================================
// S2S2S LSTM forecaster, MI355X.  Round 16 = round-15 with dec1+dec2 fused
// into ONE rec_split2 dispatch (3 dispatches total):
//   - outer p<2 loop (constant trip, unrolled -> per-phase constant headf);
//     c in regs and h in LDS across phases (same block mapping guaranteed
//     in-kernel); phase-switch = existing epilogue spin/import protocol +
//     R13-style buffer-normalization copy; per-phase hx/hxh regions.
//   - enc rec (R8 loop, ZINIT) and xproj_mega unchanged from R15.
//   Fallback: R8 chunked path (proven) if ws too small.
// Output: cols 0..75 = future-decoder head, 76..90 = 0 (ref overwrites out_f).
// ============================================================================

typedef __attribute__((ext_vector_type(8))) short short8;  // 8 x bf16
typedef __attribute__((ext_vector_type(4))) float f32x4;   // MFMA acc
typedef __attribute__((ext_vector_type(2))) unsigned int u32x2;
typedef __attribute__((ext_vector_type(4))) unsigned int u32x4;

#define L2E 1.4426950408889634f

__device__ __forceinline__ uint16_t f2bf(float f) {  // fp32 -> bf16 bits, RNE
  uint32_t x = __float_as_uint(f);
  x += 0x7fffu + ((x >> 16) & 1u);
  return (uint16_t)(x >> 16);
}
__device__ __forceinline__ uint32_t cvtpk(float lo, float hi) {  // 1-inst pack
  uint32_t r;
  asm("v_cvt_pk_bf16_f32 %0, %1, %2" : "=v"(r) : "v"(lo), "v"(hi));
  return r;
}
__device__ __forceinline__ float bfhalf(uint32_t w, int hi) {  // bf16 -> fp32
  return __uint_as_float(hi ? (w & 0xffff0000u) : (w << 16));
}
__device__ __forceinline__ f32x4 MFMA(short8 a, short8 b, f32x4 c) {
  return __builtin_amdgcn_mfma_f32_16x16x32_bf16(a, b, c, 0, 0, 0);
}
__device__ __forceinline__ float ex2(float x) { return __builtin_amdgcn_exp2f(x); }
__device__ __forceinline__ float rcp(float x) { return __builtin_amdgcn_rcpf(x); }

// pack 8 consecutive floats (16B-aligned) * scale -> short8 of bf16
__device__ __forceinline__ short8 pack8s(const float* s, float sc) {
  float4 q0 = *(const float4*)s, q1 = *(const float4*)(s + 4);
  u32x4 t;
  t[0] = cvtpk(q0.x * sc, q0.y * sc);
  t[1] = cvtpk(q0.z * sc, q0.w * sc);
  t[2] = cvtpk(q1.x * sc, q1.y * sc);
  t[3] = cvtpk(q1.z * sc, q1.w * sc);
  return *(short8*)&t;
}

// Barrier waiting only LDS ops (lgkmcnt), NOT vmcnt.
__device__ __forceinline__ void lgkm_barrier() {
  __builtin_amdgcn_sched_barrier(0);
  asm volatile("s_waitcnt lgkmcnt(0)" ::: "memory");
  __builtin_amdgcn_s_barrier();
  __builtin_amdgcn_sched_barrier(0);
}
// drain oldest vmem ops but keep 4 xp prefetch loads in flight
__device__ __forceinline__ void vm_drain4() {
  __builtin_amdgcn_sched_barrier(0);
  asm volatile("s_waitcnt vmcnt(4)" ::: "memory");
  __builtin_amdgcn_sched_barrier(0);
}

// ---------------------------------------------------------------------------
__global__ void init_kernel(float* c_state, uint16_t* h_state, float* out) {
  int i = blockIdx.x * 256 + threadIdx.x;
  if (i < 65536) { c_state[i] = 0.f; h_state[i] = 0; }
  if (i < 256 * 91) out[i] = 0.f;
}

// ---------------------------------------------------------------------------
// xproj body (proven): transposed, pre-scaled C^T fragments,
// xp[tc][btile][rowtile][lane][2], value = (x@Wih^T+b)*(g? +2log2e : -log2e).
// ---------------------------------------------------------------------------
template <int DIN>
__device__ __forceinline__ void xproj_body(
    const float* __restrict__ x, const float* __restrict__ Wih,
    const float* __restrict__ bias, uint32_t* __restrict__ xp,
    int T, int blk, int tid) {
  const int w = tid >> 6, l = tid & 63;
  const int l16 = l & 15, lg = l >> 4;
  const int tc = blk >> 1;
  const int sub = blk & 1;
  const int t = tc;
  constexpr int KT = (DIN + 31) / 32;

  short8 bfr[8][KT];
  float4 bias4[8];
#pragma unroll
  for (int ni = 0; ni < 8; ++ni) {
    const int n = (w * 8 + ni) * 16 + l16;
    bias4[ni] = *(const float4*)&bias[(w * 8 + ni) * 16 + lg * 4];
#pragma unroll
    for (int kt = 0; kt < KT; ++kt) {
      const int k0 = kt * 32 + lg * 8;
      short8 fr;
#pragma unroll
      for (int e = 0; e < 8; ++e) fr[e] = 0;
      if (k0 + 8 <= DIN) fr = pack8s(Wih + (size_t)n * DIN + k0, 1.f);
      bfr[ni][kt] = fr;
    }
  }

  for (int mi = 0; mi < 8; ++mi) {
    const int btile = sub * 8 + mi;
    const int b = btile * 16 + l16;
    short8 af[KT];
#pragma unroll
    for (int kt = 0; kt < KT; ++kt) {
      const int k0 = kt * 32 + lg * 8;
      short8 fr;
#pragma unroll
      for (int e = 0; e < 8; ++e) fr[e] = 0;
      if (k0 + 8 <= DIN) fr = pack8s(x + ((size_t)b * T + t) * DIN + k0, 1.f);
      af[kt] = fr;
    }
#pragma unroll
    for (int ni = 0; ni < 8; ++ni) {
      f32x4 acc = {0.f, 0.f, 0.f, 0.f};
#pragma unroll
      for (int kt = 0; kt < KT; ++kt) acc = MFMA(bfr[ni][kt], af[kt], acc);
      const int nt = w * 8 + ni;
      const float sc = ((nt >> 4) == 2) ? (2.f * L2E) : -L2E;
      size_t idx = ((((size_t)tc * 16 + btile) * 64 + nt) * 64 + l) * 2;
      u32x2 v;
      v[0] = cvtpk((acc[0] + bias4[ni].x) * sc, (acc[1] + bias4[ni].y) * sc);
      v[1] = cvtpk((acc[2] + bias4[ni].z) * sc, (acc[3] + bias4[ni].w) * sc);
      *(u32x2*)(xp + idx) = v;
    }
  }
}

// standalone (fallback path, chunked)
template <int DIN>
__global__ __launch_bounds__(512) void xproj_kernel(
    const float* __restrict__ x, const float* __restrict__ Wih,
    const float* __restrict__ bias, uint32_t* __restrict__ xp,
    int t0, int T) {
  const int tid = threadIdx.x;
  const int blk = blockIdx.x + t0 * 2;
  xproj_body<DIN>(x, Wih, bias, xp - (size_t)t0 * 131072, T, blk, tid);
}

// ---------------------------------------------------------------------------
// xproj_mega: one dispatch = all 3 projections + misc zeroing.
// ---------------------------------------------------------------------------
__global__ __launch_bounds__(512) void xproj_mega(
    const float* __restrict__ x0, const float* __restrict__ Wih0,
    const float* __restrict__ b0, uint32_t* __restrict__ xp0,
    const float* __restrict__ x1, const float* __restrict__ Wih1,
    const float* __restrict__ b1, uint32_t* __restrict__ xp1,
    const float* __restrict__ x2, const float* __restrict__ Wih2,
    const float* __restrict__ b2, uint32_t* __restrict__ xp2,
    float* __restrict__ out, uint32_t* __restrict__ flags,
    int T0, int T1, int T2) {
  const int tid = threadIdx.x;
  const int n0 = T0 * 2, n1 = T1 * 2, n2 = T2 * 2;
  const int b = blockIdx.x;
  if (b < n0) {
    xproj_body<64>(x0, Wih0, b0, xp0, T0, b, tid);
  } else if (b < n0 + n1) {
    xproj_body<32>(x1, Wih1, b1, xp1, T1, b - n0, tid);
  } else if (b < n0 + n1 + n2) {
    xproj_body<16>(x2, Wih2, b2, xp2, T2, b - n0 - n1, tid);
  } else {
    for (int i = tid; i < 256 * 15; i += 512)
      out[(size_t)(i / 15) * 91 + 76 + (i % 15)] = 0.f;
    if (tid < 96) flags[tid] = 0;
  }
}

// ---------------------------------------------------------------------------
// R8 rec_kernel: 16 blocks x 512 thr. ZINIT=1: zero-state prologue (enc).
// t-loop byte-identical to round 8.
// ---------------------------------------------------------------------------
template <int DO_HEAD, int ZINIT>
__global__ __launch_bounds__(512, 2) void rec_kernel(
    const uint32_t* __restrict__ xp, const float* __restrict__ Whh,
    float* __restrict__ c_state, uint16_t* __restrict__ h_state,
    float* __restrict__ out, const float* __restrict__ headW,
    const float* __restrict__ headb, int ct, int tcol0) {
  __shared__ short8 B_lds[8 * 16 * 64];
  __shared__ uint16_t h_lds[2][16][264];
  __shared__ float headbuf[2][16][8];

  const int tid = threadIdx.x, w = tid >> 6, l = tid & 63;
  const int l16 = l & 15, lg = l >> 4;
  const int blk = blockIdx.x, b0 = blk * 16;

  short8 bv[48];
#pragma unroll
  for (int g = 0; g < 4; ++g) {
    const float wsc = (g == 2) ? (2.f * L2E) : -L2E;
#pragma unroll
    for (int nt = 0; nt < 2; ++nt)
#pragma unroll
      for (int kt = 0; kt < 8; ++kt) {
        const int row = (g * 16 + w * 2 + nt) * 16 + l16;
        const float* s = Whh + (size_t)row * 256 + kt * 32 + lg * 8;
        short8 fr;
#pragma unroll
        for (int e = 0; e < 8; ++e) fr[e] = (short)f2bf(s[e] * wsc);
        const int tile = g * 2 + nt;
        if (kt <= 5) bv[tile * 6 + kt] = fr;
        else B_lds[(w * 16 + (kt - 6) * 8 + tile) * 64 + l] = fr;
      }
  }

  float c_reg[2][4];
  if (ZINIT) {
#pragma unroll
    for (int nt = 0; nt < 2; ++nt)
#pragma unroll
      for (int j = 0; j < 4; ++j) c_reg[nt][j] = 0.f;
    for (int idx = tid; idx < 16 * 264; idx += 512)
      ((uint16_t*)h_lds)[idx] = 0;
  } else {
#pragma unroll
    for (int nt = 0; nt < 2; ++nt) {
      float4 c4 = *(const float4*)&c_state[(size_t)(b0 + l16) * 256 +
                                           (w * 2 + nt) * 16 + lg * 4];
      c_reg[nt][0] = c4.x; c_reg[nt][1] = c4.y;
      c_reg[nt][2] = c4.z; c_reg[nt][3] = c4.w;
    }
    for (int idx = tid; idx < 16 * 256; idx += 512)
      h_lds[0][idx >> 8][idx & 255] = h_state[(size_t)(b0 + (idx >> 8)) * 256 + (idx & 255)];
  }
  float4 hw4[2];
#pragma unroll
  for (int nt = 0; nt < 2; ++nt)
    hw4[nt] = *(const float4*)&headW[(w * 2 + nt) * 16 + lg * 4];
  const float hb = headb[0];

  const uint32_t* xpb = xp + ((size_t)(blk * 64 + w * 2) * 64 + l) * 2;
  u32x2 xpf[2][4];
#pragma unroll
  for (int nt = 0; nt < 2; ++nt)
#pragma unroll
    for (int g = 0; g < 4; ++g)
      xpf[nt][g] = *(const u32x2*)(xpb + (size_t)g * 2048 + nt * 128);

  __syncthreads();

  for (int t = 0; t < ct; ++t) {
    const int cur = t & 1, nxt = cur ^ 1;
    const int tn = (t + 1 < ct) ? t + 1 : t;
    float hp = 0.f;

#pragma unroll
    for (int nt = 0; nt < 2; ++nt) {
      f32x4 acc[4];
#pragma unroll
      for (int g = 0; g < 4; ++g) {
        f32x4 ai;
        ai[0] = bfhalf(xpf[nt][g][0], 0);
        ai[1] = bfhalf(xpf[nt][g][0], 1);
        ai[2] = bfhalf(xpf[nt][g][1], 0);
        ai[3] = bfhalf(xpf[nt][g][1], 1);
        acc[g] = ai;
      }
#pragma unroll
      for (int kt = 0; kt <= 5; ++kt) {
        short8 hf = *(const short8*)(&h_lds[cur][l16][kt * 32 + lg * 8]);
#pragma unroll
        for (int g = 0; g < 4; ++g)
          acc[g] = MFMA(bv[(g * 2 + nt) * 6 + kt], hf, acc[g]);
      }
#pragma unroll
      for (int kt = 6; kt <= 7; ++kt) {
        short8 hf = *(const short8*)(&h_lds[cur][l16][kt * 32 + lg * 8]);
#pragma unroll
        for (int g = 0; g < 4; ++g)
          acc[g] = MFMA(B_lds[(w * 16 + (kt - 6) * 8 + g * 2 + nt) * 64 + l], hf, acc[g]);
      }

      float hv[4];
#pragma unroll
      for (int j = 0; j < 4; ++j) {
        float ei = ex2(acc[0][j]);
        float ef = ex2(acc[1][j]);
        float eg = ex2(acc[2][j]);
        float eo = ex2(acc[3][j]);
        float eip = 1.f + ei, egp = eg + 1.f, efp = 1.f + ef;
        float d1 = eip * egp;
        float R = rcp(d1 * efp);
        float sitg = (eg - 1.f) * efp * R;
        float cc = fmaf(c_reg[nt][j] * d1, R, sitg);
        c_reg[nt][j] = cc;
        float ec = ex2(cc * (2.f * L2E));
        float hh = (ec - 1.f) * rcp((1.f + eo) * (ec + 1.f));
        hv[j] = hh;
      }
      if (DO_HEAD) {
        hp = fmaf(hv[0], hw4[nt].x, hp); hp = fmaf(hv[1], hw4[nt].y, hp);
        hp = fmaf(hv[2], hw4[nt].z, hp); hp = fmaf(hv[3], hw4[nt].w, hp);
      }
      {
        u32x2 hwrd;
        hwrd[0] = cvtpk(hv[0], hv[1]);
        hwrd[1] = cvtpk(hv[2], hv[3]);
        *(u32x2*)(&h_lds[nxt][l16][(w * 2 + nt) * 16 + lg * 4]) = hwrd;
      }
#pragma unroll
      for (int g = 0; g < 4; ++g)
        xpf[nt][g] = *(const u32x2*)(xpb + (size_t)tn * 131072 + g * 2048 + nt * 128);
    }

    if (DO_HEAD) {
      float s = hp;
      s += __shfl_xor(s, 16);
      s += __shfl_xor(s, 32);
      if (lg == 0) headbuf[t & 1][l16][w] = s;
    }

    lgkm_barrier();

    if (DO_HEAD) {
      if (tid < 16) {
        const float* hbp = headbuf[t & 1][tid];
        float s = hbp[0] + hbp[1] + hbp[2] + hbp[3] + hbp[4] + hbp[5] + hbp[6] + hbp[7];
        out[(size_t)(b0 + tid) * 91 + (tcol0 + t)] = s + hb;
      }
    }
  }

#pragma unroll
  for (int nt = 0; nt < 2; ++nt) {
    float4 c4 = {c_reg[nt][0], c_reg[nt][1], c_reg[nt][2], c_reg[nt][3]};
    *(float4*)&c_state[(size_t)(b0 + l16) * 256 + (w * 2 + nt) * 16 + lg * 4] = c4;
  }
  for (int idx = tid; idx < 16 * 256; idx += 512)
    h_state[(size_t)(b0 + (idx >> 8)) * 256 + (idx & 255)] = h_lds[ct & 1][idx >> 8][idx & 255];
}

// ---------------------------------------------------------------------------
// rec_split2: BOTH decoder phases in one dispatch. 32 blocks x 512 thr.
// Per-phase hx/hxh regions (stride 32768 u64 / 1024 u32); flags slots
// (1+p)-indexed as in R15. Phase switch: epilogue-style spin/import into the
// final buffer, then normalize h to buf0 (R13 copy idiom). c in regs and h
// in LDS across phases. Inner step body verbatim R10/R15 split.
// ---------------------------------------------------------------------------
__global__ __launch_bounds__(512, 2) void rec_split2(
    const uint32_t* __restrict__ xp1g, const uint32_t* __restrict__ xp2g,
    const float* __restrict__ Whh1, const float* __restrict__ Whh2,
    const float* __restrict__ c_state, const uint16_t* __restrict__ h_state,
    float* __restrict__ out, const float* __restrict__ headW,
    const float* __restrict__ headb, uint32_t* __restrict__ flags,
    unsigned long long* __restrict__ hx, uint32_t* __restrict__ hxh,
    int T1, int T2) {
  __shared__ short8 B_lds[64 * 64];
  __shared__ uint16_t h_lds[2][16][264];
  __shared__ float headbuf[16][8];

  const int tid = threadIdx.x, w = tid >> 6, l = tid & 63;
  const int l16 = l & 15, lg = l >> 4;
  const int blk = blockIdx.x;
  const int pair = blk & 15, s = blk >> 4, sp = 1 - s;
  const int b0 = pair * 16;
  const int ctile = s * 8 + w;

  // ---- entry state from encoder ----
  float c_reg[4];
  {
    float4 c4 = *(const float4*)&c_state[(size_t)(b0 + l16) * 256 +
                                         ctile * 16 + lg * 4];
    c_reg[0] = c4.x; c_reg[1] = c4.y; c_reg[2] = c4.z; c_reg[3] = c4.w;
  }
  for (int idx = tid; idx < 16 * 256; idx += 512)
    h_lds[0][idx >> 8][idx & 255] = h_state[(size_t)(b0 + (idx >> 8)) * 256 + (idx & 255)];
  float4 hw4 = *(const float4*)&headW[ctile * 16 + lg * 4];
  const float hb = headb[0];

  float hsum_prev = 0.f;

#pragma unroll
  for (int p = 0; p < 2; ++p) {
    const float* Whh = p ? Whh2 : Whh1;
    const uint32_t* xp = p ? xp2g : xp1g;
    const int ct = p ? T2 : T1;
    const bool headf = (p == 1);
    uint32_t* const pflag = flags + ((1 + p) * 16 + pair) * 2 + sp;
    uint32_t* const myflag = flags + ((1 + p) * 16 + pair) * 2 + s;
    unsigned long long* const hxp = hx + (size_t)p * 32768;
    uint32_t* const hxhp = hxh + p * 1024;

    // ---- Whh -> prescaled bf16 fragments (B_lds reads of prior phase are
    //      retired: in-loop final lgkm_barrier / phase-switch barriers) ----
    short8 bv[24];
#pragma unroll
    for (int g = 0; g < 4; ++g) {
      const float wsc = (g == 2) ? (2.f * L2E) : -L2E;
#pragma unroll
      for (int kk = 0; kk < 8; ++kk) {
        const int kt = (kk < 4) ? (4 * s + kk) : (4 * sp + (kk - 4));
        const int row = (g * 16 + ctile) * 16 + l16;
        const float* sw = Whh + (size_t)row * 256 + kt * 32 + lg * 8;
        short8 fr;
#pragma unroll
        for (int e = 0; e < 8; ++e) fr[e] = (short)f2bf(sw[e] * wsc);
        if (kk <= 5) bv[g * 6 + kk] = fr;
        else B_lds[(w * 8 + g * 2 + (kk - 6)) * 64 + l] = fr;
      }
    }

    const uint32_t* xpb = xp + ((size_t)(pair * 64 + ctile) * 64 + l) * 2;
    u32x2 xpf[4];
#pragma unroll
    for (int g = 0; g < 4; ++g)
      xpf[g] = *(const u32x2*)(xpb + (size_t)g * 2048);

    __syncthreads();   // publish B_lds (+ h_lds on p==0 entry)

    u32x2 h_last; h_last[0] = 0; h_last[1] = 0;

    for (int t = 0; t < ct; ++t) {
      const int cur = t & 1, nxt = cur ^ 1;
      const int tn = (t + 1 < ct) ? t + 1 : t;
      const int par = t & 1;

      unsigned long long pv = 0ull;
      if (t > 0) {
        const uint32_t tgt = (uint32_t)t;
        __builtin_amdgcn_sched_barrier(0);
        uint32_t f;
        do {
          f = __hip_atomic_load(pflag, __ATOMIC_RELAXED, __HIP_MEMORY_SCOPE_AGENT);
        } while ((int)(f - tgt) < 0);
        __builtin_amdgcn_sched_barrier(0);
        pv = __hip_atomic_load(
            hxp + ((size_t)((pair * 2 + sp) * 2 + ((t - 1) & 1)) * 512) +
                (w * 4 + lg) * 16 + l16,
            __ATOMIC_RELAXED, __HIP_MEMORY_SCOPE_AGENT);
        if (headf && s == 0 && tid < 16) {
          uint32_t pp = __hip_atomic_load(
              hxhp + ((pair * 2 + sp) * 2 + ((t - 1) & 1)) * 16 + tid,
              __ATOMIC_RELAXED, __HIP_MEMORY_SCOPE_AGENT);
          out[(size_t)(b0 + tid) * 91 + (t - 1)] =
              hsum_prev + __uint_as_float(pp) + hb;
        }
      }

      f32x4 acc[4];
#pragma unroll
      for (int g = 0; g < 4; ++g) {
        f32x4 ai;
        ai[0] = bfhalf(xpf[g][0], 0);
        ai[1] = bfhalf(xpf[g][0], 1);
        ai[2] = bfhalf(xpf[g][1], 0);
        ai[3] = bfhalf(xpf[g][1], 1);
        acc[g] = ai;
      }
#pragma unroll
      for (int kk = 0; kk < 4; ++kk) {
        short8 hf = *(const short8*)(&h_lds[cur][l16][(4 * s + kk) * 32 + lg * 8]);
#pragma unroll
        for (int g = 0; g < 4; ++g)
          acc[g] = MFMA(bv[g * 6 + kk], hf, acc[g]);
      }

      if (t > 0) {
        u32x2 pw;
        pw[0] = (uint32_t)pv;
        pw[1] = (uint32_t)(pv >> 32);
        *(u32x2*)(&h_lds[cur][l16][sp * 128 + w * 16 + lg * 4]) = pw;
        lgkm_barrier();
      }

#pragma unroll
      for (int kk = 0; kk < 4; ++kk) {
        short8 hf = *(const short8*)(&h_lds[cur][l16][(4 * sp + kk) * 32 + lg * 8]);
#pragma unroll
        for (int g = 0; g < 4; ++g) {
          if (kk < 2) acc[g] = MFMA(bv[g * 6 + 4 + kk], hf, acc[g]);
          else acc[g] = MFMA(B_lds[(w * 8 + g * 2 + (kk - 2)) * 64 + l], hf, acc[g]);
        }
      }

      float hv[4];
#pragma unroll
      for (int j = 0; j < 4; ++j) {
        float ei = ex2(acc[0][j]);
        float ef = ex2(acc[1][j]);
        float eg = ex2(acc[2][j]);
        float eo = ex2(acc[3][j]);
        float eip = 1.f + ei, egp = eg + 1.f, efp = 1.f + ef;
        float d1 = eip * egp;
        float R = rcp(d1 * efp);
        float sitg = (eg - 1.f) * efp * R;
        float cc = fmaf(c_reg[j] * d1, R, sitg);
        c_reg[j] = cc;
        float ec = ex2(cc * (2.f * L2E));
        float hh = (ec - 1.f) * rcp((1.f + eo) * (ec + 1.f));
        hv[j] = hh;
      }

      h_last[0] = cvtpk(hv[0], hv[1]);
      h_last[1] = cvtpk(hv[2], hv[3]);
      *(u32x2*)(&h_lds[nxt][l16][ctile * 16 + lg * 4]) = h_last;
      {
        unsigned long long v64 =
            ((unsigned long long)h_last[1] << 32) | (unsigned long long)h_last[0];
        __hip_atomic_store(
            hxp + ((size_t)((pair * 2 + s) * 2 + par) * 512) + (w * 4 + lg) * 16 + l16,
            v64, __ATOMIC_RELAXED, __HIP_MEMORY_SCOPE_AGENT);
      }

#pragma unroll
      for (int g = 0; g < 4; ++g)
        xpf[g] = *(const u32x2*)(xpb + (size_t)tn * 131072 + g * 2048);

      if (headf) {
        float hp = fmaf(hv[0], hw4.x, fmaf(hv[1], hw4.y,
                   fmaf(hv[2], hw4.z, hv[3] * hw4.w)));
        hp += __shfl_xor(hp, 16);
        hp += __shfl_xor(hp, 32);
        if (lg == 0) headbuf[l16][w] = hp;
      }

      vm_drain4();
      lgkm_barrier();

      if (headf) {
        if (tid < 16) {
          const float* hbp = headbuf[tid];
          hsum_prev = hbp[0] + hbp[1] + hbp[2] + hbp[3] +
                      hbp[4] + hbp[5] + hbp[6] + hbp[7];
          __hip_atomic_store(hxhp + ((pair * 2 + s) * 2 + par) * 16 + tid,
                             __float_as_uint(hsum_prev), __ATOMIC_RELAXED,
                             __HIP_MEMORY_SCOPE_AGENT);
        }
        vm_drain4();
      }
      if (tid == 0)
        __hip_atomic_store(myflag, (uint32_t)(t + 1), __ATOMIC_RELAXED,
                           __HIP_MEMORY_SCOPE_AGENT);
    }

    // ---- phase switch (after p==0): complete h, normalize to buf0 ----
    if (p == 0) {
      const uint32_t tgt = (uint32_t)ct;
      __builtin_amdgcn_sched_barrier(0);
      uint32_t f;
      do {
        f = __hip_atomic_load(pflag, __ATOMIC_RELAXED, __HIP_MEMORY_SCOPE_AGENT);
      } while ((int)(f - tgt) < 0);
      __builtin_amdgcn_sched_barrier(0);
      unsigned long long pv = __hip_atomic_load(
          hxp + ((size_t)((pair * 2 + sp) * 2 + ((ct - 1) & 1)) * 512) +
              (w * 4 + lg) * 16 + l16,
          __ATOMIC_RELAXED, __HIP_MEMORY_SCOPE_AGENT);
      const int fb = ct & 1;   // buffer holding final h of phase 0
      u32x2 pw;
      pw[0] = (uint32_t)pv;
      pw[1] = (uint32_t)(pv >> 32);
      *(u32x2*)(&h_lds[fb][l16][sp * 128 + w * 16 + lg * 4]) = pw;
      lgkm_barrier();
      if (fb != 0) {
        for (int idx = tid; idx < 1024; idx += 512) {
          const int r = idx >> 6, c4v = (idx & 63) * 4;
          *(u32x2*)(&h_lds[0][r][c4v]) = *(const u32x2*)(&h_lds[1][r][c4v]);
        }
      }
      lgkm_barrier();
    }
  }

  // ---- final head column (phase 1, t = T2-1) ----
  if (s == 0 && tid < 16) {
    uint32_t* const pflag2 = flags + (2 * 16 + pair) * 2 + sp;
    const uint32_t tgt = (uint32_t)T2;
    uint32_t f;
    do {
      f = __hip_atomic_load(pflag2, __ATOMIC_RELAXED, __HIP_MEMORY_SCOPE_AGENT);
    } while ((int)(f - tgt) < 0);
    uint32_t pp = __hip_atomic_load(
        hxh + 1024 + ((pair * 2 + sp) * 2 + ((T2 - 1) & 1)) * 16 + tid,
        __ATOMIC_RELAXED, __HIP_MEMORY_SCOPE_AGENT);
    out[(size_t)(b0 + tid) * 91 + (T2 - 1)] =
        hsum_prev + __uint_as_float(pp) + hb;
  }
}

// ---------------------------------------------------------------------------
extern "C" void kernel_launch(void* const* d_in, const int* in_sizes, int n_in,
                              void* d_out, int out_size, void* d_ws, size_t ws_size,
                              hipStream_t stream) {
  const float* headW = (const float*)d_in[12];
  const float* headb = (const float*)d_in[13];
  float* out = (float*)d_out;
  char* ws = (char*)d_ws;

  const int T0 = in_sizes[0] / (256 * 64);
  const int T1 = in_sizes[1] / (256 * 32);
  const int T2 = in_sizes[2] / (256 * 16);
  const size_t s0 = (size_t)T0 << 19, s1 = (size_t)T1 << 19, s2 = (size_t)T2 << 19;
  const size_t hdr = 929792;  // state 384K + flags 4K + hx 512K + hxh 8K + pad

  if (ws_size >= hdr + s0 + s1 + s2) {
    float* c_state = (float*)ws;                           // 256 KB
    uint16_t* h_state = (uint16_t*)(ws + 262144);          // 128 KB
    uint32_t* flags = (uint32_t*)(ws + 393216);            // 4 KB slot
    unsigned long long* hx = (unsigned long long*)(ws + 397312);  // 512 KB (2 regions)
    uint32_t* hxh = (uint32_t*)(ws + 921600);              // 8 KB (2 regions)
    uint32_t* xp0 = (uint32_t*)(ws + hdr);
    uint32_t* xp1 = (uint32_t*)(ws + hdr + s0);
    uint32_t* xp2 = (uint32_t*)(ws + hdr + s0 + s1);

    // 1) all projections + misc zeroing in ONE dispatch
    const int nblk = T0 * 2 + T1 * 2 + T2 * 2 + 1;
    xproj_mega<<<dim3(nblk), 512, 0, stream>>>(
        (const float*)d_in[0], (const float*)d_in[3], (const float*)d_in[5], xp0,
        (const float*)d_in[1], (const float*)d_in[6], (const float*)d_in[8], xp1,
        (const float*)d_in[2], (const float*)d_in[9], (const float*)d_in[11], xp2,
        out, flags, T0, T1, T2);
    // 2) encoder: R8 16-block kernel, zero-init prologue
    rec_kernel<0, 1><<<16, 512, 0, stream>>>(xp0, (const float*)d_in[4], c_state,
                                             h_state, out, headW, headb, T0, 0);
    // 3) both decoders fused: 32-block split kernel
    rec_split2<<<32, 512, 0, stream>>>(xp1, xp2, (const float*)d_in[7],
                                       (const float*)d_in[10], c_state, h_state,
                                       out, headW, headb, flags, hx, hxh, T1, T2);
    return;
  }

  // ---- fallback: verbatim round-8 chunked path ----
  float* c_state = (float*)ws;                      // 256 KB
  uint16_t* h_state = (uint16_t*)(ws + 262144);     // 128 KB
  uint32_t* xp = (uint32_t*)(ws + 393216);          // chunk buffer, 512 KB per t

  int ct_max = 1;
  if (ws_size > 393216 + 512 * 1024) {
    size_t c = (ws_size - 393216) / (512 * 1024);
    ct_max = (c > 365) ? 365 : (int)c;
  }

  init_kernel<<<256, 256, 0, stream>>>(c_state, h_state, out);

  struct Phase { const float* x; const float* Wih; const float* Whh; const float* b; int T; int D; int head; };
  Phase ph[3] = {
      {(const float*)d_in[0], (const float*)d_in[3], (const float*)d_in[4], (const float*)d_in[5], T0, 64, 0},
      {(const float*)d_in[1], (const float*)d_in[6], (const float*)d_in[7], (const float*)d_in[8], T1, 32, 0},
      {(const float*)d_in[2], (const float*)d_in[9], (const float*)d_in[10], (const float*)d_in[11], T2, 16, 1},
  };

  for (int pi = 0; pi < 3; ++pi) {
    const Phase& P = ph[pi];
    for (int t0 = 0; t0 < P.T; t0 += ct_max) {
      int ct = (P.T - t0 < ct_max) ? (P.T - t0) : ct_max;
      dim3 g(ct * 2);
      if (P.D == 64)
        xproj_kernel<64><<<g, 512, 0, stream>>>(P.x, P.Wih, P.b, xp, t0, P.T);
      else if (P.D == 32)
        xproj_kernel<32><<<g, 512, 0, stream>>>(P.x, P.Wih, P.b, xp, t0, P.T);
      else
        xproj_kernel<16><<<g, 512, 0, stream>>>(P.x, P.Wih, P.b, xp, t0, P.T);
      if (P.head)
        rec_kernel<1, 0><<<16, 512, 0, stream>>>(xp, P.Whh, c_state, h_state, out,
                                                 headW, headb, ct, t0);
      else
        rec_kernel<0, 0><<<16, 512, 0, stream>>>(xp, P.Whh, c_state, h_state, out,
                                                 headW, headb, ct, t0);
    }
  }
}